// Round 17
// baseline (710.007 us; speedup 1.0000x reference)
//
#include <hip/hip_runtime.h>
#include <hip/hip_bf16.h>
#include <math.h>

#define B_ 4
#define S_ 2048
#define H_ 16
#define D_ 64
#define HD_ 1024
#define NTOK 8192  // B_*S_

#define NEGBIG (-3.0e38f)

typedef unsigned short u16;
typedef unsigned int u32;
typedef __attribute__((ext_vector_type(8))) short bf16x8;
typedef __attribute__((ext_vector_type(4))) float f32x4;
typedef __attribute__((ext_vector_type(4))) u16 u16x4;
typedef __attribute__((ext_vector_type(4))) u32 u32x4;

// ---------- helpers ----------
__device__ __forceinline__ float bf2f(u16 x){
  u32 u = ((u32)x) << 16; float f; __builtin_memcpy(&f, &u, 4); return f;
}
__device__ __forceinline__ u16 f2bf(float f){
  u32 u; __builtin_memcpy(&u, &f, 4);
  u32 r = (u + 0x7FFFu + ((u >> 16) & 1u)) >> 16;  // RNE
  return (u16)r;
}
__device__ __forceinline__ void split3s(float v, u16 &h, u16 &m, u16 &l){
  h = f2bf(v); float r  = v - bf2f(h);
  m = f2bf(r); float r2 = r - bf2f(m);
  l = f2bf(r2);
}
__device__ __forceinline__ u32 fkey(float f){
  u32 u; __builtin_memcpy(&u, &f, 4);
  return (u & 0x80000000u) ? ~u : (u | 0x80000000u);
}
__device__ __forceinline__ float keyf(u32 k){
  u32 u = (k & 0x80000000u) ? (k & 0x7FFFFFFFu) : ~k;
  float f; __builtin_memcpy(&f, &u, 4); return f;
}
// async global->LDS, 16B per lane; LDS dest = wave-uniform base + lane*16
__device__ __forceinline__ void gload16(const u16* g, u16* l){
  __builtin_amdgcn_global_load_lds(
      (const __attribute__((address_space(1))) unsigned int*)g,
      (__attribute__((address_space(3))) unsigned int*)l, 16, 0, 0);
}

// stats slots
#define ST_KSEL 0
#define ST_KPAD 1
#define ST_NCK  2
#define ST_VKEY 4
#define ST_TIES 8
#define ST_MM   12
#define ST_BIAS 36

// ws byte offsets
#define OFF_Q0   0ull                        // f32 [NTOK][64]        (-> WOT bf16)
#define OFF_K    2097152ull                  // f32 K [NTOK][HD]      (-> AO bf16)
#define OFF_V    35651584ull                 // f32 V [NTOK][HD]      (-> CVT bf16)
#define OFF_HS   69206016ull                 // bf16 planes x3 hidden (-> K0T -> CKH/CKL/CVB)
#define OFF_WP   119537664ull                // weight planes
#define OFF_QB   134742016ull                // bf16 Q [NTOK][HD]
#define OFF_IMP  151519232ull
#define OFF_LAB  151552000ull
#define OFF_SEL  151584768ull
#define OFF_ST   151617536ull
#define WS_NEED  151618560ull

// u16-unit offsets within weight-plane region
#define WKH_O 0u
#define WKM_O 1048576u
#define WKL_O 2097152u
#define WVH_O 3145728u
#define WVM_O 4194304u
#define WVL_O 5242880u
#define WQH_O 6291456u
#define WQM_O 7340032u   // [128][1024]
#define WQL_O 7471104u   // [128][1024]
#define HSPL  8388608u   // hidden plane stride (u16)

// ---------- hidden -> 3 bf16 planes (+ ST min/max init in block 0) ----------
__global__ __launch_bounds__(256) void kt_split_h(const float* __restrict__ hid,
    u16* __restrict__ p0, u16* __restrict__ p1, u16* __restrict__ p2, u32* __restrict__ st){
  if (blockIdx.x == 0 && threadIdx.x < 12)
    st[ST_MM + threadIdx.x] = ((threadIdx.x % 6) < 3) ? 0xFFFFFFFFu : 0u;
  size_t i = (size_t)blockIdx.x*256 + threadIdx.x;   // x4 elems
  float4 x = ((const float4*)hid)[i];
  u16 a0,a1,a2, b0,b1,b2, c0,c1,c2, d0,d1,d2;
  split3s(x.x, a0,a1,a2);
  split3s(x.y, b0,b1,b2);
  split3s(x.z, c0,c1,c2);
  split3s(x.w, d0,d1,d2);
  u16x4 v0 = {a0,b0,c0,d0};
  u16x4 v1 = {a1,b1,c1,d1};
  u16x4 v2 = {a2,b2,c2,d2};
  ((u16x4*)p0)[i] = v0;
  ((u16x4*)p1)[i] = v1;
  ((u16x4*)p2)[i] = v2;
}

// ---------- fused weight transpose + 3-plane split: z=0 Wk, z=1 Wv, z=2 Wq ----------
__global__ __launch_bounds__(256) void kt_twts3(const float* __restrict__ Wk,
    const float* __restrict__ Wv, const float* __restrict__ Wq, u16* __restrict__ WP){
  int z = blockIdx.z;
  const float* Win = (z==0) ? Wk : (z==1) ? Wv : Wq;
  u16* wh = WP + ((z==0) ? WKH_O : (z==1) ? WVH_O : WQH_O);
  u16* wm = WP + ((z==0) ? WKM_O : (z==1) ? WVM_O : WQM_O);
  u16* wl = WP + ((z==0) ? WKL_O : (z==1) ? WVL_O : WQL_O);
  int mlrows = (z==2) ? 128 : 1024;
  __shared__ float t[32][33];
  int bx = blockIdx.x*32, by = blockIdx.y*32;
  int tx = threadIdx.x, ty = threadIdx.y;
  #pragma unroll
  for (int i=0;i<32;i+=8) t[ty+i][tx] = Win[(size_t)(by+ty+i)*HD_ + bx+tx];
  __syncthreads();
  #pragma unroll
  for (int i=0;i<32;i+=8){
    float v = t[tx][ty+i];
    int orow = bx+ty+i;
    u16 h,m,l;
    split3s(v,h,m,l);
    wh[(size_t)orow*HD_ + by+tx] = h;
    if (orow < mlrows){
      wm[(size_t)orow*HD_ + by+tx] = m;
      wl[(size_t)orow*HD_ + by+tx] = l;
    }
  }
}

// ---------- fp32 -> bf16 transpose (Wo) ----------
__global__ __launch_bounds__(256) void kt_twto(const float* __restrict__ Win, u16* __restrict__ Wt){
  __shared__ float t[32][33];
  int bx = blockIdx.x*32, by = blockIdx.y*32;
  int tx = threadIdx.x, ty = threadIdx.y;
  #pragma unroll
  for (int i=0;i<32;i+=8) t[ty+i][tx] = Win[(size_t)(by+ty+i)*HD_ + bx+tx];
  __syncthreads();
  #pragma unroll
  for (int i=0;i<32;i+=8) Wt[(size_t)(bx+ty+i)*HD_ + by+tx] = f2bf(t[tx][ty+i]);
}

// ---------- single-tensor 6-term plane GEMM (launched for K, then V) ----------
// MFMA values and accumulation order identical to rounds 5-16 (absmax-frozen).
__global__ __launch_bounds__(256) void kt_gemm_kv1(const u16* __restrict__ HS,
    const u16* __restrict__ B0, const u16* __restrict__ B1, const u16* __restrict__ B2,
    float* __restrict__ Cf){
  int lin = blockIdx.x + (blockIdx.y << 3);
  int nl  = (lin & 7) * 64 + (lin >> 3);
  const int bx = nl & 7, by = nl >> 3;
  __shared__ u16 As0[128*32], As1[128*32], As2[128*32];
  __shared__ u16 Bs0[128*32], Bs1[128*32], Bs2[128*32];
  const int tid = threadIdx.x, lane = tid & 63;
  const int wid = tid >> 6, wr = wid >> 1, wc = wid & 1;
  const int m0 = by * 128, n0 = bx * 128;
  const int srow = lane & 15;
  const int sq   = (lane >> 4) << 3;
  const u16* gp[12];
  u16* lp[12];
  #pragma unroll
  for (int i = 0; i < 12; i++){
    int t = wid + 4*i, pl = t >> 3, g = t & 7;
    int row = g*16 + srow;
    const u16* base = (pl==0)? HS : (pl==1)? HS+HSPL : (pl==2)? HS+2u*HSPL
                     : (pl==3)? B0 : (pl==4)? B1 : B2;
    size_t roff = (pl < 3) ? (size_t)(m0+row)*HD_ : (size_t)(n0+row)*HD_;
    gp[i] = base + roff + sq;
    u16* lb = (pl==0)?As0:(pl==1)?As1:(pl==2)?As2:(pl==3)?Bs0:(pl==4)?Bs1:Bs2;
    lp[i] = lb + g*512;
  }
  f32x4 acc[4][4];
  #pragma unroll
  for (int i=0;i<4;i++)
    #pragma unroll
    for (int j=0;j<4;j++) acc[i][j] = (f32x4){0.f,0.f,0.f,0.f};
  for (int k0 = 0; k0 < HD_; k0 += 32){
    #pragma unroll
    for (int i = 0; i < 12; i++){ gload16(gp[i], lp[i]); gp[i] += 32; }
    __syncthreads();
    const int lro = lane*8;
    bf16x8 a0[4], a1[4], a2[4];
    #pragma unroll
    for (int i=0;i<4;i++){
      int ro = (wr*4 + i)*512 + lro;
      a0[i] = *(const bf16x8*)(As0 + ro);
      a1[i] = *(const bf16x8*)(As1 + ro);
      a2[i] = *(const bf16x8*)(As2 + ro);
    }
    #pragma unroll
    for (int j=0;j<4;j++){
      int co = (wc*4 + j)*512 + lro;
      bf16x8 b0 = *(const bf16x8*)(Bs0 + co);
      bf16x8 b1 = *(const bf16x8*)(Bs1 + co);
      bf16x8 b2 = *(const bf16x8*)(Bs2 + co);
      #pragma unroll
      for (int i=0;i<4;i++){
        acc[i][j] = __builtin_amdgcn_mfma_f32_16x16x32_bf16(a0[i], b0, acc[i][j], 0, 0, 0);
        acc[i][j] = __builtin_amdgcn_mfma_f32_16x16x32_bf16(a1[i], b0, acc[i][j], 0, 0, 0);
        acc[i][j] = __builtin_amdgcn_mfma_f32_16x16x32_bf16(a0[i], b1, acc[i][j], 0, 0, 0);
        acc[i][j] = __builtin_amdgcn_mfma_f32_16x16x32_bf16(a1[i], b1, acc[i][j], 0, 0, 0);
        acc[i][j] = __builtin_amdgcn_mfma_f32_16x16x32_bf16(a2[i], b0, acc[i][j], 0, 0, 0);
        acc[i][j] = __builtin_amdgcn_mfma_f32_16x16x32_bf16(a0[i], b2, acc[i][j], 0, 0, 0);
      }
    }
    __syncthreads();
  }
  const int row0 = m0 + wr*64, col0 = n0 + wc*64;
  #pragma unroll
  for (int i=0;i<4;i++)
    #pragma unroll
    for (int j=0;j<4;j++){
      int rr = row0 + i*16 + ((lane>>4)<<2);
      int cc = col0 + j*16 + (lane&15);
      #pragma unroll
      for (int r=0;r<4;r++)
        Cf[(size_t)(rr+r)*HD_ + cc] = acc[i][j][r];
    }
}

// ---------- Q plane GEMM (6-term for head-0 cols, 2-term otherwise); frozen ----------
__global__ __launch_bounds__(256) void kt_gemm_q(const u16* __restrict__ HS, const u16* __restrict__ WP,
    u16* __restrict__ qb, float* __restrict__ q0){
  int lin = blockIdx.x + (blockIdx.y << 3);
  int nl  = (lin & 7) * 64 + (lin >> 3);
  const int bx = nl & 7, by = nl >> 3;
  const u16* B0 = WP+WQH_O;
  const u16* B1 = WP+WQM_O;
  const u16* B2 = WP+WQL_O;
  const bool full = (bx == 0);
  __shared__ u16 As0[128*32], As1[128*32], As2[128*32];
  __shared__ u16 Bs0[128*32], Bs1[128*32], Bs2[128*32];
  const int tid = threadIdx.x, lane = tid & 63;
  const int wid = tid >> 6, wr = wid >> 1, wc = wid & 1;
  const int m0 = by * 128, n0 = bx * 128;
  const int srow = lane & 15;
  const int sq   = (lane >> 4) << 3;
  const u16* gp[12];
  u16* lp[12];
  if (full){
    #pragma unroll
    for (int i = 0; i < 12; i++){
      int t = wid + 4*i, pl = t >> 3, g = t & 7;
      int row = g*16 + srow;
      const u16* base = (pl==0)? HS : (pl==1)? HS+HSPL : (pl==2)? HS+2u*HSPL
                       : (pl==3)? B0 : (pl==4)? B1 : B2;
      size_t roff = (pl < 3) ? (size_t)(m0+row)*HD_ : (size_t)(n0+row)*HD_;
      gp[i] = base + roff + sq;
      u16* lb = (pl==0)?As0:(pl==1)?As1:(pl==2)?As2:(pl==3)?Bs0:(pl==4)?Bs1:Bs2;
      lp[i] = lb + g*512;
    }
  } else {
    #pragma unroll
    for (int i = 0; i < 6; i++){
      int t = wid + 4*i, p3 = t >> 3, g = t & 7;
      int pl = (p3 == 2) ? 3 : p3;
      int row = g*16 + srow;
      const u16* base = (pl==0)? HS : (pl==1)? HS+HSPL : B0;
      size_t roff = (pl < 3) ? (size_t)(m0+row)*HD_ : (size_t)(n0+row)*HD_;
      gp[i] = base + roff + sq;
      u16* lb = (pl==0)?As0:(pl==1)?As1:Bs0;
      lp[i] = lb + g*512;
    }
  }
  f32x4 acc[4][4];
  #pragma unroll
  for (int i=0;i<4;i++)
    #pragma unroll
    for (int j=0;j<4;j++) acc[i][j] = (f32x4){0.f,0.f,0.f,0.f};
  for (int k0 = 0; k0 < HD_; k0 += 32){
    if (full){
      #pragma unroll
      for (int i = 0; i < 12; i++){ gload16(gp[i], lp[i]); gp[i] += 32; }
    } else {
      #pragma unroll
      for (int i = 0; i < 6; i++){ gload16(gp[i], lp[i]); gp[i] += 32; }
    }
    __syncthreads();
    const int lro = lane*8;
    bf16x8 a0[4], a1[4], a2[4];
    #pragma unroll
    for (int i=0;i<4;i++){
      int ro = (wr*4 + i)*512 + lro;
      a0[i] = *(const bf16x8*)(As0 + ro);
      a1[i] = *(const bf16x8*)(As1 + ro);
      if (full) a2[i] = *(const bf16x8*)(As2 + ro);
    }
    #pragma unroll
    for (int j=0;j<4;j++){
      int co = (wc*4 + j)*512 + lro;
      bf16x8 b0 = *(const bf16x8*)(Bs0 + co);
      if (full){
        bf16x8 b1 = *(const bf16x8*)(Bs1 + co);
        bf16x8 b2 = *(const bf16x8*)(Bs2 + co);
        #pragma unroll
        for (int i=0;i<4;i++){
          acc[i][j] = __builtin_amdgcn_mfma_f32_16x16x32_bf16(a0[i], b0, acc[i][j], 0, 0, 0);
          acc[i][j] = __builtin_amdgcn_mfma_f32_16x16x32_bf16(a1[i], b0, acc[i][j], 0, 0, 0);
          acc[i][j] = __builtin_amdgcn_mfma_f32_16x16x32_bf16(a0[i], b1, acc[i][j], 0, 0, 0);
          acc[i][j] = __builtin_amdgcn_mfma_f32_16x16x32_bf16(a1[i], b1, acc[i][j], 0, 0, 0);
          acc[i][j] = __builtin_amdgcn_mfma_f32_16x16x32_bf16(a2[i], b0, acc[i][j], 0, 0, 0);
          acc[i][j] = __builtin_amdgcn_mfma_f32_16x16x32_bf16(a0[i], b2, acc[i][j], 0, 0, 0);
        }
      } else {
        #pragma unroll
        for (int i=0;i<4;i++){
          acc[i][j] = __builtin_amdgcn_mfma_f32_16x16x32_bf16(a0[i], b0, acc[i][j], 0, 0, 0);
          acc[i][j] = __builtin_amdgcn_mfma_f32_16x16x32_bf16(a1[i], b0, acc[i][j], 0, 0, 0);
        }
      }
    }
    __syncthreads();
  }
  const int row0 = m0 + wr*64, col0 = n0 + wc*64;
  #pragma unroll
  for (int i=0;i<4;i++)
    #pragma unroll
    for (int j=0;j<4;j++){
      int rr = row0 + i*16 + ((lane>>4)<<2);
      int cc = col0 + j*16 + (lane&15);
      #pragma unroll
      for (int r=0;r<4;r++){
        float v = acc[i][j][r];
        qb[(size_t)(rr+r)*HD_ + cc] = f2bf(v);
        if (cc < 64) q0[(size_t)(rr+r)*64 + cc] = v;
      }
    }
}

// ---------- O-projection GEMM: gload16 fragment-order staging + swizzle ----------
__global__ __launch_bounds__(256) void kt_gemm_o(const u16* __restrict__ A, const u16* __restrict__ Bt,
    float* __restrict__ out){
  int lin = blockIdx.x + (blockIdx.y << 3);
  int nl  = (lin & 7) * 64 + (lin >> 3);
  const int bx = nl & 7, by = nl >> 3;
  __shared__ u16 As[128*32];
  __shared__ u16 Bs[128*32];
  const int tid = threadIdx.x, lane = tid & 63;
  const int wid = tid >> 6, wr = wid >> 1, wc = wid & 1;
  const int m0 = by * 128, n0 = bx * 128;
  const u16* gp[4];
  u16* lp[4];
  #pragma unroll
  for (int i = 0; i < 4; i++){
    int t = wid + 4*i, pl = t >> 3, g = t & 7;
    int row = g*16 + (lane & 15);
    gp[i] = (pl ? (Bt + (size_t)(n0+row)*HD_) : (A + (size_t)(m0+row)*HD_)) + ((lane>>4)<<3);
    lp[i] = (pl ? Bs : As) + g*512;
  }
  f32x4 acc[4][4];
  #pragma unroll
  for (int i=0;i<4;i++)
    #pragma unroll
    for (int j=0;j<4;j++) acc[i][j] = (f32x4){0.f,0.f,0.f,0.f};
  for (int k0 = 0; k0 < HD_; k0 += 32){
    #pragma unroll
    for (int i = 0; i < 4; i++){ gload16(gp[i], lp[i]); gp[i] += 32; }
    __syncthreads();
    const int lro = lane*8;
    bf16x8 af[4], bg[4];
    #pragma unroll
    for (int i=0;i<4;i++){
      af[i] = *(const bf16x8*)(As + (wr*4 + i)*512 + lro);
      bg[i] = *(const bf16x8*)(Bs + (wc*4 + i)*512 + lro);
    }
    #pragma unroll
    for (int i=0;i<4;i++)
      #pragma unroll
      for (int j=0;j<4;j++)
        acc[i][j] = __builtin_amdgcn_mfma_f32_16x16x32_bf16(af[i], bg[j], acc[i][j], 0, 0, 0);
    __syncthreads();
  }
  const int row0 = m0 + wr*64, col0 = n0 + wc*64;
  #pragma unroll
  for (int i=0;i<4;i++)
    #pragma unroll
    for (int j=0;j<4;j++){
      int rr = row0 + i*16 + ((lane>>4)<<2);
      int cc = col0 + j*16 + (lane&15);
      #pragma unroll
      for (int r=0;r<4;r++)
        out[(size_t)(rr+r)*HD_ + cc] = acc[i][j][r];
    }
}

// ---------- k0t: [B][64][S] fp32 transpose of K head 0 ----------
__global__ __launch_bounds__(256) void kt_k0t(const float* __restrict__ Kf, float* __restrict__ k0t){
  __shared__ float t[32][33];
  int b = blockIdx.z, s0 = blockIdx.x*32, d0 = blockIdx.y*32;
  int tx = threadIdx.x, ty = threadIdx.y;
  #pragma unroll
  for (int i=0;i<32;i+=8) t[ty+i][tx] = Kf[((size_t)b*S_ + s0+ty+i)*HD_ + d0+tx];
  __syncthreads();
  #pragma unroll
  for (int i=0;i<32;i+=8) k0t[((size_t)b*D_ + d0+ty+i)*S_ + s0+tx] = t[tx][ty+i];
}

// ---------- bias[b] ----------
__global__ __launch_bounds__(1024) void kt_bias(const float* __restrict__ q0, const float* __restrict__ wimp,
    const float* __restrict__ bimp, u32* __restrict__ st){
  int b = blockIdx.x;
  int d = threadIdx.x & 63, sg = threadIdx.x >> 6;
  float acc = 0.f;
  for (int s = sg; s < S_; s += 16) acc += q0[((size_t)b*S_ + s)*64 + d];
  __shared__ float red[16][64];
  red[sg][d] = acc;
  __syncthreads();
  if (sg == 0){
    float tot = 0.f;
    #pragma unroll
    for (int i=0;i<16;i++) tot += red[i][d];
    float term = (tot / (float)S_) * wimp[d];
    #pragma unroll
    for (int off=32; off; off>>=1) term += __shfl_xor(term, off);
    if (d == 0) ((float*)st)[ST_BIAS + b] = term + bimp[0];
  }
}

// ---------- importance (fp32), prompt_mask width auto-detect ----------
__global__ __launch_bounds__(256) void kt_imp(const float* __restrict__ q0, const float* __restrict__ k0t,
    const int* __restrict__ pm, const u32* __restrict__ st, float* __restrict__ imp){
  int b = blockIdx.y, r0 = blockIdx.x * 16;
  int tid = threadIdx.x, lane = tid & 63, w = tid >> 6;
  __shared__ float qs[16][64];
  __shared__ float pms[S_];
  __shared__ int mode8;
  if (tid == 0) mode8 = 0;
  __syncthreads();
  const unsigned char* pmb = (const unsigned char*)pm;
  int flag = 0;
  for (int i = tid; i < S_; i += 256) if (i & 3) flag |= pmb[i];
  if (flag) atomicOr(&mode8, 1);
  for (int i = tid; i < 16*64; i += 256){
    int rr = i >> 6, dd = i & 63;
    qs[rr][dd] = q0[((size_t)b*S_ + r0 + rr)*64 + dd];
  }
  __syncthreads();
  if (mode8){ for (int i = tid; i < S_; i += 256) pms[i] = pmb[i] ? 1.f : 0.f; }
  else      { for (int i = tid; i < S_; i += 256) pms[i] = pm[i]  ? 1.f : 0.f; }
  __syncthreads();
  float sc[4][32];
  #pragma unroll
  for (int r=0;r<4;r++)
    #pragma unroll
    for (int j=0;j<32;j++) sc[r][j] = 0.f;
  const float* kb = k0t + (size_t)b*D_*S_;
  for (int d=0; d<64; d++){
    const float* krow = kb + (size_t)d*S_;
    float kx[32];
    #pragma unroll
    for (int j=0;j<32;j++) kx[j] = krow[lane + 64*j];
    #pragma unroll
    for (int r=0;r<4;r++){
      float qd = qs[w*4 + r][d];
      #pragma unroll
      for (int j=0;j<32;j++) sc[r][j] = fmaf(qd, kx[j], sc[r][j]);
    }
  }
  float bias = ((const float*)st)[ST_BIAS + b];
  #pragma unroll
  for (int r=0;r<4;r++){
    float mx = NEGBIG;
    #pragma unroll
    for (int j=0;j<32;j++) mx = fmaxf(mx, sc[r][j]);
    #pragma unroll
    for (int off=32; off; off>>=1) mx = fmaxf(mx, __shfl_xor(mx, off));
    mx *= 0.125f;
    float se = 0.f, sp = 0.f;
    #pragma unroll
    for (int j=0;j<32;j++){
      float e = expf(sc[r][j]*0.125f - mx);
      se += e;
      sp += e * pms[lane + 64*j];
    }
    #pragma unroll
    for (int off=32; off; off>>=1){ se += __shfl_xor(se, off); sp += __shfl_xor(sp, off); }
    if (lane == 0) imp[(size_t)b*S_ + r0 + w*4 + r] = sp/se + bias;
  }
}

// ---------- stats ----------
__global__ __launch_bounds__(1024) void kt_stats(const float* __restrict__ imp, u32* __restrict__ st){
  __shared__ u32 keys[NTOK];
  __shared__ u32 res2[2];
  __shared__ int cnts[4];
  int tid = threadIdx.x, lane = tid & 63, w = tid >> 6;
  for (int i = tid; i < NTOK; i += 1024) keys[i] = fkey(imp[i]);
  __syncthreads();
  if (w < 2){
    int kk = 4095 + w;
    u32 lo = 0u, hi = 0xFFFFFFFFu;
    while (lo < hi){
      u32 mid = lo + ((hi - lo) >> 1);
      int c = 0;
      for (int i = lane; i < NTOK; i += 64) c += (keys[i] <= mid) ? 1 : 0;
      #pragma unroll
      for (int off=32; off; off>>=1) c += __shfl_xor(c, off);
      if (c >= kk + 1) hi = mid; else lo = mid + 1;
    }
    if (lane == 0) res2[w] = lo;
  }
  __syncthreads();
  float a = keyf(res2[0]), bq = keyf(res2[1]);
  float thr = __fadd_rn(a, __fmul_rn(__fsub_rn(bq, a), 0.5f));
  u32 tkey = fkey(thr);
  if (w < 4){
    int c = 0;
    for (int i = lane; i < S_; i += 64) c += (keys[w*S_ + i] >= tkey) ? 1 : 0;
    #pragma unroll
    for (int off=32; off; off>>=1) c += __shfl_xor(c, off);
    if (lane == 0) cnts[w] = c;
  }
  __syncthreads();
  int ksel = max(max(cnts[0], cnts[1]), max(cnts[2], cnts[3]));
  if (tid == 0){
    int kpad = (ksel + 63) & ~63;
    ((int*)st)[ST_KSEL] = ksel;
    ((int*)st)[ST_KPAD] = kpad;
    ((int*)st)[ST_NCK]  = kpad >> 6;
  }
  if (w < 4){
    int kk = S_ - ksel;
    u32 lo = 0u, hi = 0xFFFFFFFFu;
    while (lo < hi){
      u32 mid = lo + ((hi - lo) >> 1);
      int c = 0;
      for (int i = lane; i < S_; i += 64) c += (keys[w*S_ + i] <= mid) ? 1 : 0;
      #pragma unroll
      for (int off=32; off; off>>=1) c += __shfl_xor(c, off);
      if (c >= kk + 1) hi = mid; else lo = mid + 1;
    }
    int cle = 0;
    for (int i = lane; i < S_; i += 64) cle += (keys[w*S_ + i] <= lo) ? 1 : 0;
    #pragma unroll
    for (int off=32; off; off>>=1) cle += __shfl_xor(cle, off);
    if (lane == 0){
      st[ST_VKEY + w] = lo;
      ((int*)st)[ST_TIES + w] = ksel - (S_ - cle);
    }
  }
}

// ---------- select ----------
__global__ __launch_bounds__(1024) void kt_select(const float* __restrict__ imp, const u32* __restrict__ st,
    int* __restrict__ sel, u32* __restrict__ lab){
  int b = blockIdx.x, tid = threadIdx.x, lane = tid & 63, w = tid >> 6;
  u32 vkey = st[ST_VKEY + b];
  int ties = ((const int*)st)[ST_TIES + b];
  int s0 = tid*2, s1 = s0 + 1;
  float f0 = imp[(size_t)b*S_ + s0], f1 = imp[(size_t)b*S_ + s1];
  lab[(size_t)b*S_ + s0] = (f0 > 0.7f) ? 2u : ((f0 >= 0.3f) ? 1u : 0u);
  lab[(size_t)b*S_ + s1] = (f1 > 0.7f) ? 2u : ((f1 >= 0.3f) ? 1u : 0u);
  u32 k0 = fkey(f0), k1 = fkey(f1);
  int g0 = (k0 > vkey), g1 = (k1 > vkey);
  int t0 = (k0 == vkey), t1 = (k1 == vkey);
  __shared__ int wtot[16];
  int tsum = t0 + t1, incl = tsum;
  #pragma unroll
  for (int off=1; off<64; off<<=1){ int nv = __shfl_up(incl, off); if (lane >= off) incl += nv; }
  if (lane == 63) wtot[w] = incl;
  __syncthreads();
  int woff = 0;
  for (int i=0;i<w;i++) woff += wtot[i];
  int tie0 = woff + incl - tsum;
  int tie1 = tie0 + t0;
  int sf0 = g0 | (t0 & ((tie0 < ties) ? 1 : 0));
  int sf1 = g1 | (t1 & ((tie1 < ties) ? 1 : 0));
  __syncthreads();
  int ssum = sf0 + sf1; incl = ssum;
  #pragma unroll
  for (int off=1; off<64; off<<=1){ int nv = __shfl_up(incl, off); if (lane >= off) incl += nv; }
  if (lane == 63) wtot[w] = incl;
  __syncthreads();
  woff = 0;
  for (int i=0;i<w;i++) woff += wtot[i];
  int p0 = woff + incl - ssum;
  if (sf0) sel[(size_t)b*S_ + p0] = s0;
  if (sf1) sel[(size_t)b*S_ + p0 + sf0] = s1;
}

// ---------- per-level global min/max: 256 blocks (atomic contention fix) ----------
__global__ __launch_bounds__(256) void kt_minmax(const float* __restrict__ Kf, const float* __restrict__ Vf,
    const u32* __restrict__ lab, u32* __restrict__ st){
  u32 mn[6], mx[6];
  #pragma unroll
  for (int q=0;q<6;q++){ mn[q] = 0xFFFFFFFFu; mx[q] = 0u; }
  const int n4 = NTOK * HD_ / 4;
  for (int i = blockIdx.x*blockDim.x + threadIdx.x; i < n4; i += gridDim.x*blockDim.x){
    u32 l = min(lab[i >> 8], 2u);
    float4 kv = ((const float4*)Kf)[i];
    float4 vv = ((const float4*)Vf)[i];
    u32 a0=fkey(kv.x), a1=fkey(kv.y), a2=fkey(kv.z), a3=fkey(kv.w);
    u32 klo = min(min(a0,a1),min(a2,a3)), khi = max(max(a0,a1),max(a2,a3));
    if (klo < mn[l]) mn[l] = klo;
    if (khi > mx[l]) mx[l] = khi;
    u32 b0=fkey(vv.x), b1=fkey(vv.y), b2=fkey(vv.z), b3=fkey(vv.w);
    u32 vlo = min(min(b0,b1),min(b2,b3)), vhi = max(max(b0,b1),max(b2,b3));
    if (vlo < mn[3+l]) mn[3+l] = vlo;
    if (vhi > mx[3+l]) mx[3+l] = vhi;
  }
  #pragma unroll
  for (int q=0;q<6;q++){
    #pragma unroll
    for (int off=32; off; off>>=1){
      u32 om = (u32)__shfl_xor((int)mn[q], off); if (om < mn[q]) mn[q] = om;
      u32 oM = (u32)__shfl_xor((int)mx[q], off); if (oM > mx[q]) mx[q] = oM;
    }
  }
  __shared__ u32 smn[4][6], smx[4][6];
  int lane = threadIdx.x & 63, w = threadIdx.x >> 6;
  if (lane == 0){
    #pragma unroll
    for (int q=0;q<6;q++){ smn[w][q]=mn[q]; smx[w][q]=mx[q]; }
  }
  __syncthreads();
  if (threadIdx.x < 6){
    int q = threadIdx.x;
    u32 m = smn[0][q], M = smx[0][q];
    #pragma unroll
    for (int i=1;i<4;i++){ if (smn[i][q] < m) m = smn[i][q]; if (smx[i][q] > M) M = smx[i][q]; }
    int minSlot = ST_MM + ((q < 3) ? q : q + 3);
    atomicMin(&st[minSlot], m);
    atomicMax(&st[minSlot + 3], M);
  }
}

// ---------- scales from ST_MM (bit-identical to former kt_finalize math) ----------
__device__ __forceinline__ void scales_for(const u32* st, u32 l, float &qmx,
    float &sK, float &zK, float &sV, float &zV){
  qmx = (l==0) ? 3.f : (l==1) ? 15.f : 255.f;
  u32 mnk = st[ST_MM + l], mxk = st[ST_MM + 3 + l];
  sK = 1.f; zK = 0.f;
  if (!(mnk == 0xFFFFFFFFu || mxk == 0u)){
    float tmn = keyf(mnk), tmx = keyf(mxk);
    if (tmx != tmn){ sK = __fdiv_rn(__fsub_rn(tmx, tmn), qmx); zK = __fdiv_rn(-tmn, sK); }
  }
  u32 mnv = st[ST_MM + 6 + l], mxv = st[ST_MM + 9 + l];
  sV = 1.f; zV = 0.f;
  if (!(mnv == 0xFFFFFFFFu || mxv == 0u)){
    float tmn = keyf(mnv), tmx = keyf(mxv);
    if (tmx != tmn){ sV = __fdiv_rn(__fsub_rn(tmx, tmn), qmx); zV = __fdiv_rn(-tmn, sV); }
  }
}

__device__ __forceinline__ float dqz(float x, float s, float z, float q){
  float t = rintf(__fadd_rn(__fdiv_rn(x, s), z));
  t = fminf(fmaxf(t, 0.f), q);
  return __fmul_rn(__fsub_rn(t, z), s);
}

// ---------- gather + quant-dequant; K hi/lo, V single (scales inlined) ----------
__global__ __launch_bounds__(256) void kt_buildck(const float* __restrict__ Kf, const float* __restrict__ Vf,
    const int* __restrict__ sel, const u32* __restrict__ lab, const u32* __restrict__ st,
    u16* __restrict__ ckh, u16* __restrict__ ckl, u16* __restrict__ cvb){
  int b = blockIdx.z, j = blockIdx.y;
  int ksel = ((const int*)st)[ST_KSEL], kpad = ((const int*)st)[ST_KPAD];
  if (j >= kpad) return;
  int dd = threadIdx.x * 4;
  size_t oo = ((size_t)b*S_ + j)*HD_ + dd;
  if (j >= ksel){
    u16x4 z4 = {0,0,0,0};
    *(u16x4*)(ckh + oo) = z4;
    *(u16x4*)(ckl + oo) = z4;
    *(u16x4*)(cvb + oo) = z4;
    return;
  }
  int s = sel[(size_t)b*S_ + j];
  u32 l = min(lab[(size_t)b*S_ + s], 2u);
  float qmx, sK, zK, sV, zV;
  scales_for(st, l, qmx, sK, zK, sV, zV);
  float4 kv = *(const float4*)(Kf + ((size_t)b*S_ + s)*HD_ + dd);
  float4 vv = *(const float4*)(Vf + ((size_t)b*S_ + s)*HD_ + dd);
  float kd0 = dqz(kv.x,sK,zK,qmx), kd1 = dqz(kv.y,sK,zK,qmx), kd2 = dqz(kv.z,sK,zK,qmx), kd3 = dqz(kv.w,sK,zK,qmx);
  u16 h0 = f2bf(kd0), h1 = f2bf(kd1), h2 = f2bf(kd2), h3 = f2bf(kd3);
  u16x4 kh = {h0, h1, h2, h3};
  u16x4 kl = {f2bf(kd0 - bf2f(h0)), f2bf(kd1 - bf2f(h1)), f2bf(kd2 - bf2f(h2)), f2bf(kd3 - bf2f(h3))};
  u16x4 vo = {f2bf(dqz(vv.x,sV,zV,qmx)), f2bf(dqz(vv.y,sV,zV,qmx)),
              f2bf(dqz(vv.z,sV,zV,qmx)), f2bf(dqz(vv.w,sV,zV,qmx))};
  *(u16x4*)(ckh + oo) = kh;
  *(u16x4*)(ckl + oo) = kl;
  *(u16x4*)(cvb + oo) = vo;
}

// ---------- bf16 transpose of V ----------
__global__ __launch_bounds__(256) void kt_cvt(const u16* __restrict__ cvb, u16* __restrict__ cvT,
    const u32* __restrict__ st){
  int kpad = ((const int*)st)[ST_KPAD];
  int j0 = blockIdx.x*32;
  if (j0 >= kpad) return;
  int d0 = blockIdx.y*32, b = blockIdx.z;
  __shared__ u16 t[32][33];
  int tx = threadIdx.x, ty = threadIdx.y;
  #pragma unroll
  for (int i=0;i<32;i+=8) t[ty+i][tx] = cvb[((size_t)b*S_ + j0+ty+i)*HD_ + d0+tx];
  __syncthreads();
  #pragma unroll
  for (int i=0;i<32;i+=8) cvT[((size_t)b*HD_ + d0+ty+i)*S_ + j0+tx] = t[tx][ty+i];
}

// ---------- flash attention: K dbuf LDS, V direct-to-VGPR, per-qstep P buffers ----------
// Values and MFMA order identical to round 16 (V bits unchanged; P trunc-split kept).
#define ATTN_QSTEP(KSH, KSL, PWH, PWL, QA0, QA1, MRUN, LRUN, OARR, MASKQ)          \
  {                                                                                \
    f32x4 sc[4];                                                                   \
    const int fro = ((lane>>3)&1)*512 + (((lane>>4)*8 + (lane&7))<<3);             \
    __builtin_amdgcn_s_setprio(1);                                                 \
    _Pragma("unroll")                                                              \
    for (int nt=0; nt<4; nt++){                                                    \
      int ro = nt*1024 + fro;                                                      \
      bf16x8 bh0 = *(const bf16x8*)(KSH + ro);                                     \
      bf16x8 bh1 = *(const bf16x8*)(KSH + ro + 256);                               \
      bf16x8 bl0 = *(const bf16x8*)(KSL + ro);                                     \
      bf16x8 bl1 = *(const bf16x8*)(KSL + ro + 256);                               \
      f32x4 zzv = (f32x4){0.f,0.f,0.f,0.f};                                        \
      zzv = __builtin_amdgcn_mfma_f32_16x16x32_bf16(QA0, bh0, zzv, 0, 0, 0);       \
      zzv = __builtin_amdgcn_mfma_f32_16x16x32_bf16(QA1, bh1, zzv, 0, 0, 0);       \
      zzv = __builtin_amdgcn_mfma_f32_16x16x32_bf16(QA0, bl0, zzv, 0, 0, 0);       \
      zzv = __builtin_amdgcn_mfma_f32_16x16x32_bf16(QA1, bl1, zzv, 0, 0, 0);       \
      sc[nt] = zzv;                                                                \
    }                                                                              \
    __builtin_amdgcn_s_setprio(0);                                                 \
    float cm[4] = {NEGBIG,NEGBIG,NEGBIG,NEGBIG};                                   \
    _Pragma("unroll")                                                              \
    for (int nt=0; nt<4; nt++){                                                    \
      bool valid = MASKQ ? ((c*64 + nt*16 + (lane&15)) < ksel) : true;             \
      _Pragma("unroll")                                                            \
      for (int r=0;r<4;r++){                                                       \
        float x = valid ? sc[nt][r]*0.125f : NEGBIG;                               \
        sc[nt][r] = x;                                                             \
        cm[r] = fmaxf(cm[r], x);                                                   \
      }                                                                            \
    }                                                                              \
    _Pragma("unroll")                                                              \
    for (int r=0;r<4;r++){                                                         \
      _Pragma("unroll")                                                            \
      for (int off=1; off<16; off<<=1) cm[r] = fmaxf(cm[r], __shfl_xor(cm[r], off));\
    }                                                                              \
    float alpha[4], rs[4];                                                         \
    _Pragma("unroll")                                                              \
    for (int r=0;r<4;r++){                                                         \
      float mn = fmaxf(MRUN[r], cm[r]);                                            \
      alpha[r] = __expf(MRUN[r] - mn);                                             \
      MRUN[r] = mn;                                                                \
      rs[r] = 0.f;                                                                 \
    }                                                                              \
    _Pragma("unroll")                                                              \
    for (int nt=0; nt<4; nt++)                                                     \
      _Pragma("unroll")                                                            \
      for (int r=0;r<4;r++){                                                       \
        float p = __expf(sc[nt][r] - MRUN[r]);                                     \
        sc[nt][r] = p;                                                             \
        rs[r] += p;                                                                \
      }                                                                            \
    _Pragma("unroll")                                                              \
    for (int r=0;r<4;r++){                                                         \
      _Pragma("unroll")                                                            \
      for (int off=1; off<16; off<<=1) rs[r] += __shfl_xor(rs[r], off);            \
      LRUN[r] = LRUN[r]*alpha[r] + rs[r];                                          \
    }                                                                              \
    _Pragma("unroll")                                                              \
    for (int dt=0; dt<4; dt++)                                                     \
      _Pragma("unroll")                                                            \
      for (int r=0;r<4;r++) OARR[dt][r] *= alpha[r];                               \
    _Pragma("unroll")                                                              \
    for (int nt=0; nt<4; nt++)                                                     \
      _Pragma("unroll")                                                            \
      for (int r=0;r<4;r++){                                                       \
        float p = sc[nt][r];                                                       \
        u32 pu; __builtin_memcpy(&pu, &p, 4);                                      \
        u32 hm = pu & 0xFFFF0000u;                                                 \
        float rh; __builtin_memcpy(&rh, &hm, 4);                                   \
        float rl = p - rh;                                                         \
        u32 lu; __builtin_memcpy(&lu, &rl, 4);                                     \
        int o2 = (((lane>>4)<<2) + r)*72 + nt*16 + (lane&15);                      \
        PWH[o2] = (u16)(pu >> 16);                                                 \
        PWL[o2] = (u16)(lu >> 16);                                                 \
      }                                                                            \
    bf16x8 pa0h = *(const bf16x8*)(PWH + (lane&15)*72 + ((lane>>4)<<3));           \
    bf16x8 pa1h = *(const bf16x8*)(PWH + (lane&15)*72 + 32 + ((lane>>4)<<3));      \
    bf16x8 pa0l = *(const bf16x8*)(PWL + (lane&15)*72 + ((lane>>4)<<3));           \
    bf16x8 pa1l = *(const bf16x8*)(PWL + (lane&15)*72 + 32 + ((lane>>4)<<3));      \
    __builtin_amdgcn_s_setprio(1);                                                 \
    _Pragma("unroll")                                                              \
    for (int dt=0; dt<4; dt++){                                                    \
      bf16x8 v0 = vr[2*dt];                                                        \
      bf16x8 v1 = vr[2*dt+1];                                                      \
      OARR[dt] = __builtin_amdgcn_mfma_f32_16x16x32_bf16(pa0h, v0, OARR[dt], 0, 0, 0);\
      OARR[dt] = __builtin_amdgcn_mfma_f32_16x16x32_bf16(pa1h, v1, OARR[dt], 0, 0, 0);\
      OARR[dt] = __builtin_amdgcn_mfma_f32_16x16x32_bf16(pa0l, v0, OARR[dt], 0, 0, 0);\
      OARR[dt] = __builtin_amdgcn_mfma_f32_16x16x32_bf16(pa1l, v1, OARR[dt], 0, 0, 0);\
    }                                                                              \
    __builtin_amdgcn_s_setprio(0);                                                 \
  }

__global__ __launch_bounds__(256) void kt_attn(const u16* __restrict__ qb, const u16* __restrict__ ckh,
    const u16* __restrict__ ckl, const u16* __restrict__ cvT, const u32* __restrict__ st,
    u16* __restrict__ ao){
  int m0 = blockIdx.x * 128, h = blockIdx.y, b = blockIdx.z;
  int ksel = ((const int*)st)[ST_KSEL], nck = ((const int*)st)[ST_NCK];
  int tid = threadIdx.x, lane = tid & 63, w = tid >> 6;
  __shared__ u16 cksh[2*4096];
  __shared__ u16 cksl[2*4096];
  __shared__ u16 psh0[4][16*72];
  __shared__ u16 psl0[4][16*72];
  __shared__ u16 psh1[4][16*72];
  __shared__ u16 psl1[4][16*72];
  // K staging pointers (4 subtile-loads per wave per chunk: hi x2, lo x2)
  const u16* gp[4];
  u16* lp[4];
  #pragma unroll
  for (int i = 0; i < 4; i++){
    int t = w + 4*i, pl = t >> 3, g = t & 7;
    if (pl == 0){
      gp[i] = ckh + ((size_t)b*S_ + g*8 + (lane&7))*HD_ + h*64 + ((lane>>3)<<3);
      lp[i] = cksh + g*512;
    } else {
      gp[i] = ckl + ((size_t)b*S_ + g*8 + (lane&7))*HD_ + h*64 + ((lane>>3)<<3);
      lp[i] = cksl + g*512;
    }
  }
  // V direct-read row pointers (per dt), advance +64 per chunk
  const u16* vp[4];
  #pragma unroll
  for (int dt = 0; dt < 4; dt++)
    vp[dt] = cvT + ((size_t)b*HD_ + h*64 + dt*16 + (lane&15))*S_ + ((lane>>4)<<3);
  const u16* qrow0 = qb + ((size_t)b*S_ + m0      + w*16 + (lane&15))*HD_ + h*64;
  const u16* qrow1 = qb + ((size_t)b*S_ + m0 + 64 + w*16 + (lane&15))*HD_ + h*64;
  bf16x8 q0a = *(const bf16x8*)(qrow0 + ((lane>>4)<<3));
  bf16x8 q0b = *(const bf16x8*)(qrow0 + 32 + ((lane>>4)<<3));
  bf16x8 q1a = *(const bf16x8*)(qrow1 + ((lane>>4)<<3));
  bf16x8 q1b = *(const bf16x8*)(qrow1 + 32 + ((lane>>4)<<3));
  f32x4 o0[4], o1[4];
  #pragma unroll
  for (int dt=0; dt<4; dt++){ o0[dt] = (f32x4){0.f,0.f,0.f,0.f}; o1[dt] = (f32x4){0.f,0.f,0.f,0.f}; }
  float m0r[4] = {NEGBIG,NEGBIG,NEGBIG,NEGBIG};
  float m1r[4] = {NEGBIG,NEGBIG,NEGBIG,NEGBIG};
  float l0r[4] = {0.f,0.f,0.f,0.f};
  float l1r[4] = {0.f,0.f,0.f,0.f};
  u16* pwh0 = &psh0[w][0];
  u16* pwl0 = &psl0[w][0];
  u16* pwh1 = &psh1[w][0];
  u16* pwl1 = &psl1[w][0];
  const int nfull = ksel >> 6;
  // prologue: stage K chunk 0 into buffer 0
  #pragma unroll
  for (int i = 0; i < 4; i++){ gload16(gp[i], lp[i]); gp[i] += 64*HD_; }
  __syncthreads();
  for (int c = 0; c < nck; c++){
    int cur = c & 1, nxt = cur ^ 1;
    // V for this chunk: direct global -> VGPR (shared by both qsteps)
    bf16x8 vr[8];
    #pragma unroll
    for (int dt = 0; dt < 4; dt++){
      vr[2*dt]   = *(const bf16x8*)(vp[dt]);
      vr[2*dt+1] = *(const bf16x8*)(vp[dt] + 32);
      vp[dt] += 64;
    }
    // K prefetch for chunk c+1
    if (c + 1 < nck){
      #pragma unroll
      for (int i = 0; i < 4; i++){ gload16(gp[i], lp[i] + nxt*4096); gp[i] += 64*HD_; }
    }
    const u16* ksh = cksh + cur*4096;
    const u16* ksl = cksl + cur*4096;
    if (c < nfull){
      ATTN_QSTEP(ksh, ksl, pwh0, pwl0, q0a, q0b, m0r, l0r, o0, 0)
      ATTN_QSTEP(ksh, ksl, pwh1, pwl1, q1a, q1b, m1r, l1r, o1, 0)
    } else {
      ATTN_QSTEP(ksh, ksl, pwh0, pwl0, q0a, q0b, m0r, l0r, o0, 1)
      ATTN_QSTEP(ksh, ksl, pwh1, pwl1, q1a, q1b, m1r, l1r, o1, 1)
    }
    __syncthreads();
  }
  #pragma unroll
  for (int dt=0; dt<4; dt++)
    #pragma unroll
    for (int r=0;r<4;r++){
      int dd = dt*16 + (lane&15);
      int row0 = m0 + w*16 + ((lane>>4)<<2) + r;
      float v0 = o0[dt][r] / fmaxf(l0r[r], 1e-37f);
      ao[((size_t)b*S_ + row0)*HD_ + h*64 + dd] = f2bf(v0);
      int row1 = row0 + 64;
      float v1 = o1[dt][r] / fmaxf(l1r[r], 1e-37f);
      ao[((size_t)b*S_ + row1)*HD_ + h*64 + dd] = f2bf(v1);
    }
}

// ---------- launch ----------
extern "C" void kernel_launch(void* const* d_in, const int* in_sizes, int n_in,
                              void* d_out, int out_size, void* d_ws, size_t ws_size,
                              hipStream_t stream){
  if (ws_size < WS_NEED) return;
  const float* hid  = (const float*)d_in[0];
  const float* Wq   = (const float*)d_in[1];
  const float* Wk   = (const float*)d_in[2];
  const float* Wv   = (const float*)d_in[3];
  const float* Wo   = (const float*)d_in[4];
  const float* wimp = (const float*)d_in[5];
  const float* bimp = (const float*)d_in[6];
  const int*   pm   = (const int*)d_in[7];

  char* ws = (char*)d_ws;
  float* Q0  = (float*)(ws + OFF_Q0);
  float* Kf  = (float*)(ws + OFF_K);
  float* Vf  = (float*)(ws + OFF_V);
  u16*   HS  = (u16*)(ws + OFF_HS);
  u16*   WP  = (u16*)(ws + OFF_WP);
  u16*   QB  = (u16*)(ws + OFF_QB);
  float* IMP = (float*)(ws + OFF_IMP);
  u32*   LAB = (u32*)(ws + OFF_LAB);
  int*   SEL = (int*)(ws + OFF_SEL);
  u32*   ST  = (u32*)(ws + OFF_ST);
  // aliases (lifetime-checked):
  float* K0T = (float*)(ws + OFF_HS);                 // HS dead after gemm_q/kv
  u16*   CKH = (u16*)(ws + OFF_HS);                   // from buildck on
  u16*   CKL = (u16*)(ws + OFF_HS + 16777216ull);
  u16*   CVB = (u16*)(ws + OFF_HS + 33554432ull);
  u16*   CVT = (u16*)(ws + OFF_V);                    // Vf dead after buildck
  u16*   AO  = (u16*)(ws + OFF_K);                    // Kf dead after buildck
  u16*   WOT = (u16*)(ws + OFF_Q0);                   // Q0 dead after imp

  dim3 tb32(32, 8);
  kt_split_h<<<8192, 256, 0, stream>>>(hid, HS, HS + HSPL, HS + 2u*HSPL, ST);
  kt_twts3<<<dim3(32,32,3), tb32, 0, stream>>>(Wk, Wv, Wq, WP);
  kt_gemm_kv1<<<dim3(8,64), 256, 0, stream>>>(HS, WP+WKH_O, WP+WKM_O, WP+WKL_O, Kf);
  kt_gemm_kv1<<<dim3(8,64), 256, 0, stream>>>(HS, WP+WVH_O, WP+WVM_O, WP+WVL_O, Vf);
  kt_gemm_q<<<dim3(8,64), 256, 0, stream>>>(HS, WP, QB, Q0);
  kt_k0t<<<dim3(64,2,4), tb32, 0, stream>>>(Kf, K0T);
  kt_bias<<<4, 1024, 0, stream>>>(Q0, wimp, bimp, ST);
  kt_imp<<<dim3(128,4), 256, 0, stream>>>(Q0, K0T, pm, ST, IMP);
  kt_stats<<<1, 1024, 0, stream>>>(IMP, ST);
  kt_select<<<4, 1024, 0, stream>>>(IMP, ST, SEL, LAB);
  kt_minmax<<<256, 256, 0, stream>>>(Kf, Vf, LAB, ST);
  kt_buildck<<<dim3(1,2048,4), 256, 0, stream>>>(Kf, Vf, SEL, LAB, ST, CKH, CKL, CVB);
  kt_cvt<<<dim3(64,32,4), tb32, 0, stream>>>(CVB, CVT, ST);
  kt_attn<<<dim3(16,16,4), 256, 0, stream>>>(QB, CKH, CKL, CVT, ST, AO);
  kt_twto<<<dim3(32,32), tb32, 0, stream>>>(Wo, WOT);
  kt_gemm_o<<<dim3(8,64), 256, 0, stream>>>(AO, WOT, (float*)d_out);
}

// Round 18
// 684.758 us; speedup vs baseline: 1.0369x; 1.0369x over previous
//
#include <hip/hip_runtime.h>
#include <hip/hip_bf16.h>
#include <math.h>

#define B_ 4
#define S_ 2048
#define H_ 16
#define D_ 64
#define HD_ 1024
#define NTOK 8192  // B_*S_

#define NEGBIG (-3.0e38f)

typedef unsigned short u16;
typedef unsigned int u32;
typedef __attribute__((ext_vector_type(8))) short bf16x8;
typedef __attribute__((ext_vector_type(4))) float f32x4;
typedef __attribute__((ext_vector_type(4))) u16 u16x4;
typedef __attribute__((ext_vector_type(4))) u32 u32x4;

// ---------- helpers ----------
__device__ __forceinline__ float bf2f(u16 x){
  u32 u = ((u32)x) << 16; float f; __builtin_memcpy(&f, &u, 4); return f;
}
__device__ __forceinline__ u16 f2bf(float f){
  u32 u; __builtin_memcpy(&u, &f, 4);
  u32 r = (u + 0x7FFFu + ((u >> 16) & 1u)) >> 16;  // RNE
  return (u16)r;
}
__device__ __forceinline__ void split3s(float v, u16 &h, u16 &m, u16 &l){
  h = f2bf(v); float r  = v - bf2f(h);
  m = f2bf(r); float r2 = r - bf2f(m);
  l = f2bf(r2);
}
__device__ __forceinline__ u32 fkey(float f){
  u32 u; __builtin_memcpy(&u, &f, 4);
  return (u & 0x80000000u) ? ~u : (u | 0x80000000u);
}
__device__ __forceinline__ float keyf(u32 k){
  u32 u = (k & 0x80000000u) ? (k & 0x7FFFFFFFu) : ~k;
  float f; __builtin_memcpy(&f, &u, 4); return f;
}
// async global->LDS, 16B per lane; LDS dest = wave-uniform base + lane*16
__device__ __forceinline__ void gload16(const u16* g, u16* l){
  __builtin_amdgcn_global_load_lds(
      (const __attribute__((address_space(1))) unsigned int*)g,
      (__attribute__((address_space(3))) unsigned int*)l, 16, 0, 0);
}

// stats slots
#define ST_KSEL 0
#define ST_KPAD 1
#define ST_NCK  2
#define ST_VKEY 4
#define ST_TIES 8
#define ST_MM   12
#define ST_BIAS 36

// ws byte offsets
#define OFF_Q0   0ull                        // f32 [NTOK][64]        (-> WOT bf16)
#define OFF_K    2097152ull                  // f32 K [NTOK][HD]      (-> AO bf16)
#define OFF_V    35651584ull                 // f32 V [NTOK][HD]      (-> CVT bf16)
#define OFF_HS   69206016ull                 // bf16 planes x3 hidden (-> K0T -> CKH/CKL/CVB)
#define OFF_WP   119537664ull                // weight planes
#define OFF_QB   134742016ull                // bf16 Q [NTOK][HD]
#define OFF_IMP  151519232ull
#define OFF_LAB  151552000ull
#define OFF_SEL  151584768ull
#define OFF_ST   151617536ull
#define WS_NEED  151618560ull

// u16-unit offsets within weight-plane region
#define WKH_O 0u
#define WKM_O 1048576u
#define WKL_O 2097152u
#define WVH_O 3145728u
#define WVM_O 4194304u
#define WVL_O 5242880u
#define WQH_O 6291456u
#define WQM_O 7340032u   // [128][1024]
#define WQL_O 7471104u   // [128][1024]
#define HSPL  8388608u   // hidden plane stride (u16)

// ---------- hidden -> 3 bf16 planes (+ ST min/max init in block 0) ----------
__global__ __launch_bounds__(256) void kt_split_h(const float* __restrict__ hid,
    u16* __restrict__ p0, u16* __restrict__ p1, u16* __restrict__ p2, u32* __restrict__ st){
  if (blockIdx.x == 0 && threadIdx.x < 12)
    st[ST_MM + threadIdx.x] = ((threadIdx.x % 6) < 3) ? 0xFFFFFFFFu : 0u;
  size_t i = (size_t)blockIdx.x*256 + threadIdx.x;   // x4 elems
  float4 x = ((const float4*)hid)[i];
  u16 a0,a1,a2, b0,b1,b2, c0,c1,c2, d0,d1,d2;
  split3s(x.x, a0,a1,a2);
  split3s(x.y, b0,b1,b2);
  split3s(x.z, c0,c1,c2);
  split3s(x.w, d0,d1,d2);
  u16x4 v0 = {a0,b0,c0,d0};
  u16x4 v1 = {a1,b1,c1,d1};
  u16x4 v2 = {a2,b2,c2,d2};
  ((u16x4*)p0)[i] = v0;
  ((u16x4*)p1)[i] = v1;
  ((u16x4*)p2)[i] = v2;
}

// ---------- fused weight transpose + 3-plane split: z=0 Wk, z=1 Wv, z=2 Wq ----------
__global__ __launch_bounds__(256) void kt_twts3(const float* __restrict__ Wk,
    const float* __restrict__ Wv, const float* __restrict__ Wq, u16* __restrict__ WP){
  int z = blockIdx.z;
  const float* Win = (z==0) ? Wk : (z==1) ? Wv : Wq;
  u16* wh = WP + ((z==0) ? WKH_O : (z==1) ? WVH_O : WQH_O);
  u16* wm = WP + ((z==0) ? WKM_O : (z==1) ? WVM_O : WQM_O);
  u16* wl = WP + ((z==0) ? WKL_O : (z==1) ? WVL_O : WQL_O);
  int mlrows = (z==2) ? 128 : 1024;
  __shared__ float t[32][33];
  int bx = blockIdx.x*32, by = blockIdx.y*32;
  int tx = threadIdx.x, ty = threadIdx.y;
  #pragma unroll
  for (int i=0;i<32;i+=8) t[ty+i][tx] = Win[(size_t)(by+ty+i)*HD_ + bx+tx];
  __syncthreads();
  #pragma unroll
  for (int i=0;i<32;i+=8){
    float v = t[tx][ty+i];
    int orow = bx+ty+i;
    u16 h,m,l;
    split3s(v,h,m,l);
    wh[(size_t)orow*HD_ + by+tx] = h;
    if (orow < mlrows){
      wm[(size_t)orow*HD_ + by+tx] = m;
      wl[(size_t)orow*HD_ + by+tx] = l;
    }
  }
}

// ---------- fp32 -> bf16 transpose (Wo) ----------
__global__ __launch_bounds__(256) void kt_twto(const float* __restrict__ Win, u16* __restrict__ Wt){
  __shared__ float t[32][33];
  int bx = blockIdx.x*32, by = blockIdx.y*32;
  int tx = threadIdx.x, ty = threadIdx.y;
  #pragma unroll
  for (int i=0;i<32;i+=8) t[ty+i][tx] = Win[(size_t)(by+ty+i)*HD_ + bx+tx];
  __syncthreads();
  #pragma unroll
  for (int i=0;i<32;i+=8) Wt[(size_t)(bx+ty+i)*HD_ + by+tx] = f2bf(t[tx][ty+i]);
}

// ---------- single-tensor 6-term plane GEMM (launched for K, then V) ----------
// MFMA values and accumulation order identical to rounds 5-16 (absmax-frozen).
__global__ __launch_bounds__(256) void kt_gemm_kv1(const u16* __restrict__ HS,
    const u16* __restrict__ B0, const u16* __restrict__ B1, const u16* __restrict__ B2,
    float* __restrict__ Cf){
  int lin = blockIdx.x + (blockIdx.y << 3);
  int nl  = (lin & 7) * 64 + (lin >> 3);
  const int bx = nl & 7, by = nl >> 3;
  __shared__ u16 As0[128*32], As1[128*32], As2[128*32];
  __shared__ u16 Bs0[128*32], Bs1[128*32], Bs2[128*32];
  const int tid = threadIdx.x, lane = tid & 63;
  const int wid = tid >> 6, wr = wid >> 1, wc = wid & 1;
  const int m0 = by * 128, n0 = bx * 128;
  const int srow = lane & 15;
  const int sq   = (lane >> 4) << 3;
  const u16* gp[12];
  u16* lp[12];
  #pragma unroll
  for (int i = 0; i < 12; i++){
    int t = wid + 4*i, pl = t >> 3, g = t & 7;
    int row = g*16 + srow;
    const u16* base = (pl==0)? HS : (pl==1)? HS+HSPL : (pl==2)? HS+2u*HSPL
                     : (pl==3)? B0 : (pl==4)? B1 : B2;
    size_t roff = (pl < 3) ? (size_t)(m0+row)*HD_ : (size_t)(n0+row)*HD_;
    gp[i] = base + roff + sq;
    u16* lb = (pl==0)?As0:(pl==1)?As1:(pl==2)?As2:(pl==3)?Bs0:(pl==4)?Bs1:Bs2;
    lp[i] = lb + g*512;
  }
  f32x4 acc[4][4];
  #pragma unroll
  for (int i=0;i<4;i++)
    #pragma unroll
    for (int j=0;j<4;j++) acc[i][j] = (f32x4){0.f,0.f,0.f,0.f};
  for (int k0 = 0; k0 < HD_; k0 += 32){
    #pragma unroll
    for (int i = 0; i < 12; i++){ gload16(gp[i], lp[i]); gp[i] += 32; }
    __syncthreads();
    const int lro = lane*8;
    bf16x8 a0[4], a1[4], a2[4];
    #pragma unroll
    for (int i=0;i<4;i++){
      int ro = (wr*4 + i)*512 + lro;
      a0[i] = *(const bf16x8*)(As0 + ro);
      a1[i] = *(const bf16x8*)(As1 + ro);
      a2[i] = *(const bf16x8*)(As2 + ro);
    }
    #pragma unroll
    for (int j=0;j<4;j++){
      int co = (wc*4 + j)*512 + lro;
      bf16x8 b0 = *(const bf16x8*)(Bs0 + co);
      bf16x8 b1 = *(const bf16x8*)(Bs1 + co);
      bf16x8 b2 = *(const bf16x8*)(Bs2 + co);
      #pragma unroll
      for (int i=0;i<4;i++){
        acc[i][j] = __builtin_amdgcn_mfma_f32_16x16x32_bf16(a0[i], b0, acc[i][j], 0, 0, 0);
        acc[i][j] = __builtin_amdgcn_mfma_f32_16x16x32_bf16(a1[i], b0, acc[i][j], 0, 0, 0);
        acc[i][j] = __builtin_amdgcn_mfma_f32_16x16x32_bf16(a0[i], b1, acc[i][j], 0, 0, 0);
        acc[i][j] = __builtin_amdgcn_mfma_f32_16x16x32_bf16(a1[i], b1, acc[i][j], 0, 0, 0);
        acc[i][j] = __builtin_amdgcn_mfma_f32_16x16x32_bf16(a2[i], b0, acc[i][j], 0, 0, 0);
        acc[i][j] = __builtin_amdgcn_mfma_f32_16x16x32_bf16(a0[i], b2, acc[i][j], 0, 0, 0);
      }
    }
    __syncthreads();
  }
  const int row0 = m0 + wr*64, col0 = n0 + wc*64;
  #pragma unroll
  for (int i=0;i<4;i++)
    #pragma unroll
    for (int j=0;j<4;j++){
      int rr = row0 + i*16 + ((lane>>4)<<2);
      int cc = col0 + j*16 + (lane&15);
      #pragma unroll
      for (int r=0;r<4;r++)
        Cf[(size_t)(rr+r)*HD_ + cc] = acc[i][j][r];
    }
}

// ---------- Q plane GEMM (6-term for head-0 cols, 2-term otherwise); frozen ----------
__global__ __launch_bounds__(256) void kt_gemm_q(const u16* __restrict__ HS, const u16* __restrict__ WP,
    u16* __restrict__ qb, float* __restrict__ q0){
  int lin = blockIdx.x + (blockIdx.y << 3);
  int nl  = (lin & 7) * 64 + (lin >> 3);
  const int bx = nl & 7, by = nl >> 3;
  const u16* B0 = WP+WQH_O;
  const u16* B1 = WP+WQM_O;
  const u16* B2 = WP+WQL_O;
  const bool full = (bx == 0);
  __shared__ u16 As0[128*32], As1[128*32], As2[128*32];
  __shared__ u16 Bs0[128*32], Bs1[128*32], Bs2[128*32];
  const int tid = threadIdx.x, lane = tid & 63;
  const int wid = tid >> 6, wr = wid >> 1, wc = wid & 1;
  const int m0 = by * 128, n0 = bx * 128;
  const int srow = lane & 15;
  const int sq   = (lane >> 4) << 3;
  const u16* gp[12];
  u16* lp[12];
  if (full){
    #pragma unroll
    for (int i = 0; i < 12; i++){
      int t = wid + 4*i, pl = t >> 3, g = t & 7;
      int row = g*16 + srow;
      const u16* base = (pl==0)? HS : (pl==1)? HS+HSPL : (pl==2)? HS+2u*HSPL
                       : (pl==3)? B0 : (pl==4)? B1 : B2;
      size_t roff = (pl < 3) ? (size_t)(m0+row)*HD_ : (size_t)(n0+row)*HD_;
      gp[i] = base + roff + sq;
      u16* lb = (pl==0)?As0:(pl==1)?As1:(pl==2)?As2:(pl==3)?Bs0:(pl==4)?Bs1:Bs2;
      lp[i] = lb + g*512;
    }
  } else {
    #pragma unroll
    for (int i = 0; i < 6; i++){
      int t = wid + 4*i, p3 = t >> 3, g = t & 7;
      int pl = (p3 == 2) ? 3 : p3;
      int row = g*16 + srow;
      const u16* base = (pl==0)? HS : (pl==1)? HS+HSPL : B0;
      size_t roff = (pl < 3) ? (size_t)(m0+row)*HD_ : (size_t)(n0+row)*HD_;
      gp[i] = base + roff + sq;
      u16* lb = (pl==0)?As0:(pl==1)?As1:Bs0;
      lp[i] = lb + g*512;
    }
  }
  f32x4 acc[4][4];
  #pragma unroll
  for (int i=0;i<4;i++)
    #pragma unroll
    for (int j=0;j<4;j++) acc[i][j] = (f32x4){0.f,0.f,0.f,0.f};
  for (int k0 = 0; k0 < HD_; k0 += 32){
    if (full){
      #pragma unroll
      for (int i = 0; i < 12; i++){ gload16(gp[i], lp[i]); gp[i] += 32; }
    } else {
      #pragma unroll
      for (int i = 0; i < 6; i++){ gload16(gp[i], lp[i]); gp[i] += 32; }
    }
    __syncthreads();
    const int lro = lane*8;
    bf16x8 a0[4], a1[4], a2[4];
    #pragma unroll
    for (int i=0;i<4;i++){
      int ro = (wr*4 + i)*512 + lro;
      a0[i] = *(const bf16x8*)(As0 + ro);
      a1[i] = *(const bf16x8*)(As1 + ro);
      if (full) a2[i] = *(const bf16x8*)(As2 + ro);
    }
    #pragma unroll
    for (int j=0;j<4;j++){
      int co = (wc*4 + j)*512 + lro;
      bf16x8 b0 = *(const bf16x8*)(Bs0 + co);
      if (full){
        bf16x8 b1 = *(const bf16x8*)(Bs1 + co);
        bf16x8 b2 = *(const bf16x8*)(Bs2 + co);
        #pragma unroll
        for (int i=0;i<4;i++){
          acc[i][j] = __builtin_amdgcn_mfma_f32_16x16x32_bf16(a0[i], b0, acc[i][j], 0, 0, 0);
          acc[i][j] = __builtin_amdgcn_mfma_f32_16x16x32_bf16(a1[i], b0, acc[i][j], 0, 0, 0);
          acc[i][j] = __builtin_amdgcn_mfma_f32_16x16x32_bf16(a0[i], b1, acc[i][j], 0, 0, 0);
          acc[i][j] = __builtin_amdgcn_mfma_f32_16x16x32_bf16(a1[i], b1, acc[i][j], 0, 0, 0);
          acc[i][j] = __builtin_amdgcn_mfma_f32_16x16x32_bf16(a2[i], b0, acc[i][j], 0, 0, 0);
          acc[i][j] = __builtin_amdgcn_mfma_f32_16x16x32_bf16(a0[i], b2, acc[i][j], 0, 0, 0);
        }
      } else {
        #pragma unroll
        for (int i=0;i<4;i++){
          acc[i][j] = __builtin_amdgcn_mfma_f32_16x16x32_bf16(a0[i], b0, acc[i][j], 0, 0, 0);
          acc[i][j] = __builtin_amdgcn_mfma_f32_16x16x32_bf16(a1[i], b0, acc[i][j], 0, 0, 0);
        }
      }
    }
    __syncthreads();
  }
  const int row0 = m0 + wr*64, col0 = n0 + wc*64;
  #pragma unroll
  for (int i=0;i<4;i++)
    #pragma unroll
    for (int j=0;j<4;j++){
      int rr = row0 + i*16 + ((lane>>4)<<2);
      int cc = col0 + j*16 + (lane&15);
      #pragma unroll
      for (int r=0;r<4;r++){
        float v = acc[i][j][r];
        qb[(size_t)(rr+r)*HD_ + cc] = f2bf(v);
        if (cc < 64) q0[(size_t)(rr+r)*64 + cc] = v;
      }
    }
}

// ---------- O-projection GEMM: gload16 fragment-order staging + swizzle ----------
__global__ __launch_bounds__(256) void kt_gemm_o(const u16* __restrict__ A, const u16* __restrict__ Bt,
    float* __restrict__ out){
  int lin = blockIdx.x + (blockIdx.y << 3);
  int nl  = (lin & 7) * 64 + (lin >> 3);
  const int bx = nl & 7, by = nl >> 3;
  __shared__ u16 As[128*32];
  __shared__ u16 Bs[128*32];
  const int tid = threadIdx.x, lane = tid & 63;
  const int wid = tid >> 6, wr = wid >> 1, wc = wid & 1;
  const int m0 = by * 128, n0 = bx * 128;
  const u16* gp[4];
  u16* lp[4];
  #pragma unroll
  for (int i = 0; i < 4; i++){
    int t = wid + 4*i, pl = t >> 3, g = t & 7;
    int row = g*16 + (lane & 15);
    gp[i] = (pl ? (Bt + (size_t)(n0+row)*HD_) : (A + (size_t)(m0+row)*HD_)) + ((lane>>4)<<3);
    lp[i] = (pl ? Bs : As) + g*512;
  }
  f32x4 acc[4][4];
  #pragma unroll
  for (int i=0;i<4;i++)
    #pragma unroll
    for (int j=0;j<4;j++) acc[i][j] = (f32x4){0.f,0.f,0.f,0.f};
  for (int k0 = 0; k0 < HD_; k0 += 32){
    #pragma unroll
    for (int i = 0; i < 4; i++){ gload16(gp[i], lp[i]); gp[i] += 32; }
    __syncthreads();
    const int lro = lane*8;
    bf16x8 af[4], bg[4];
    #pragma unroll
    for (int i=0;i<4;i++){
      af[i] = *(const bf16x8*)(As + (wr*4 + i)*512 + lro);
      bg[i] = *(const bf16x8*)(Bs + (wc*4 + i)*512 + lro);
    }
    #pragma unroll
    for (int i=0;i<4;i++)
      #pragma unroll
      for (int j=0;j<4;j++)
        acc[i][j] = __builtin_amdgcn_mfma_f32_16x16x32_bf16(af[i], bg[j], acc[i][j], 0, 0, 0);
    __syncthreads();
  }
  const int row0 = m0 + wr*64, col0 = n0 + wc*64;
  #pragma unroll
  for (int i=0;i<4;i++)
    #pragma unroll
    for (int j=0;j<4;j++){
      int rr = row0 + i*16 + ((lane>>4)<<2);
      int cc = col0 + j*16 + (lane&15);
      #pragma unroll
      for (int r=0;r<4;r++)
        out[(size_t)(rr+r)*HD_ + cc] = acc[i][j][r];
    }
}

// ---------- k0t: [B][64][S] fp32 transpose of K head 0 ----------
__global__ __launch_bounds__(256) void kt_k0t(const float* __restrict__ Kf, float* __restrict__ k0t){
  __shared__ float t[32][33];
  int b = blockIdx.z, s0 = blockIdx.x*32, d0 = blockIdx.y*32;
  int tx = threadIdx.x, ty = threadIdx.y;
  #pragma unroll
  for (int i=0;i<32;i+=8) t[ty+i][tx] = Kf[((size_t)b*S_ + s0+ty+i)*HD_ + d0+tx];
  __syncthreads();
  #pragma unroll
  for (int i=0;i<32;i+=8) k0t[((size_t)b*D_ + d0+ty+i)*S_ + s0+tx] = t[tx][ty+i];
}

// ---------- bias[b] ----------
__global__ __launch_bounds__(1024) void kt_bias(const float* __restrict__ q0, const float* __restrict__ wimp,
    const float* __restrict__ bimp, u32* __restrict__ st){
  int b = blockIdx.x;
  int d = threadIdx.x & 63, sg = threadIdx.x >> 6;
  float acc = 0.f;
  for (int s = sg; s < S_; s += 16) acc += q0[((size_t)b*S_ + s)*64 + d];
  __shared__ float red[16][64];
  red[sg][d] = acc;
  __syncthreads();
  if (sg == 0){
    float tot = 0.f;
    #pragma unroll
    for (int i=0;i<16;i++) tot += red[i][d];
    float term = (tot / (float)S_) * wimp[d];
    #pragma unroll
    for (int off=32; off; off>>=1) term += __shfl_xor(term, off);
    if (d == 0) ((float*)st)[ST_BIAS + b] = term + bimp[0];
  }
}

// ---------- importance (fp32), prompt_mask width auto-detect ----------
__global__ __launch_bounds__(256) void kt_imp(const float* __restrict__ q0, const float* __restrict__ k0t,
    const int* __restrict__ pm, const u32* __restrict__ st, float* __restrict__ imp){
  int b = blockIdx.y, r0 = blockIdx.x * 16;
  int tid = threadIdx.x, lane = tid & 63, w = tid >> 6;
  __shared__ float qs[16][64];
  __shared__ float pms[S_];
  __shared__ int mode8;
  if (tid == 0) mode8 = 0;
  __syncthreads();
  const unsigned char* pmb = (const unsigned char*)pm;
  int flag = 0;
  for (int i = tid; i < S_; i += 256) if (i & 3) flag |= pmb[i];
  if (flag) atomicOr(&mode8, 1);
  for (int i = tid; i < 16*64; i += 256){
    int rr = i >> 6, dd = i & 63;
    qs[rr][dd] = q0[((size_t)b*S_ + r0 + rr)*64 + dd];
  }
  __syncthreads();
  if (mode8){ for (int i = tid; i < S_; i += 256) pms[i] = pmb[i] ? 1.f : 0.f; }
  else      { for (int i = tid; i < S_; i += 256) pms[i] = pm[i]  ? 1.f : 0.f; }
  __syncthreads();
  float sc[4][32];
  #pragma unroll
  for (int r=0;r<4;r++)
    #pragma unroll
    for (int j=0;j<32;j++) sc[r][j] = 0.f;
  const float* kb = k0t + (size_t)b*D_*S_;
  for (int d=0; d<64; d++){
    const float* krow = kb + (size_t)d*S_;
    float kx[32];
    #pragma unroll
    for (int j=0;j<32;j++) kx[j] = krow[lane + 64*j];
    #pragma unroll
    for (int r=0;r<4;r++){
      float qd = qs[w*4 + r][d];
      #pragma unroll
      for (int j=0;j<32;j++) sc[r][j] = fmaf(qd, kx[j], sc[r][j]);
    }
  }
  float bias = ((const float*)st)[ST_BIAS + b];
  #pragma unroll
  for (int r=0;r<4;r++){
    float mx = NEGBIG;
    #pragma unroll
    for (int j=0;j<32;j++) mx = fmaxf(mx, sc[r][j]);
    #pragma unroll
    for (int off=32; off; off>>=1) mx = fmaxf(mx, __shfl_xor(mx, off));
    mx *= 0.125f;
    float se = 0.f, sp = 0.f;
    #pragma unroll
    for (int j=0;j<32;j++){
      float e = expf(sc[r][j]*0.125f - mx);
      se += e;
      sp += e * pms[lane + 64*j];
    }
    #pragma unroll
    for (int off=32; off; off>>=1){ se += __shfl_xor(se, off); sp += __shfl_xor(sp, off); }
    if (lane == 0) imp[(size_t)b*S_ + r0 + w*4 + r] = sp/se + bias;
  }
}

// ---------- stats ----------
__global__ __launch_bounds__(1024) void kt_stats(const float* __restrict__ imp, u32* __restrict__ st){
  __shared__ u32 keys[NTOK];
  __shared__ u32 res2[2];
  __shared__ int cnts[4];
  int tid = threadIdx.x, lane = tid & 63, w = tid >> 6;
  for (int i = tid; i < NTOK; i += 1024) keys[i] = fkey(imp[i]);
  __syncthreads();
  if (w < 2){
    int kk = 4095 + w;
    u32 lo = 0u, hi = 0xFFFFFFFFu;
    while (lo < hi){
      u32 mid = lo + ((hi - lo) >> 1);
      int c = 0;
      for (int i = lane; i < NTOK; i += 64) c += (keys[i] <= mid) ? 1 : 0;
      #pragma unroll
      for (int off=32; off; off>>=1) c += __shfl_xor(c, off);
      if (c >= kk + 1) hi = mid; else lo = mid + 1;
    }
    if (lane == 0) res2[w] = lo;
  }
  __syncthreads();
  float a = keyf(res2[0]), bq = keyf(res2[1]);
  float thr = __fadd_rn(a, __fmul_rn(__fsub_rn(bq, a), 0.5f));
  u32 tkey = fkey(thr);
  if (w < 4){
    int c = 0;
    for (int i = lane; i < S_; i += 64) c += (keys[w*S_ + i] >= tkey) ? 1 : 0;
    #pragma unroll
    for (int off=32; off; off>>=1) c += __shfl_xor(c, off);
    if (lane == 0) cnts[w] = c;
  }
  __syncthreads();
  int ksel = max(max(cnts[0], cnts[1]), max(cnts[2], cnts[3]));
  if (tid == 0){
    int kpad = (ksel + 63) & ~63;
    ((int*)st)[ST_KSEL] = ksel;
    ((int*)st)[ST_KPAD] = kpad;
    ((int*)st)[ST_NCK]  = kpad >> 6;
  }
  if (w < 4){
    int kk = S_ - ksel;
    u32 lo = 0u, hi = 0xFFFFFFFFu;
    while (lo < hi){
      u32 mid = lo + ((hi - lo) >> 1);
      int c = 0;
      for (int i = lane; i < S_; i += 64) c += (keys[w*S_ + i] <= mid) ? 1 : 0;
      #pragma unroll
      for (int off=32; off; off>>=1) c += __shfl_xor(c, off);
      if (c >= kk + 1) hi = mid; else lo = mid + 1;
    }
    int cle = 0;
    for (int i = lane; i < S_; i += 64) cle += (keys[w*S_ + i] <= lo) ? 1 : 0;
    #pragma unroll
    for (int off=32; off; off>>=1) cle += __shfl_xor(cle, off);
    if (lane == 0){
      st[ST_VKEY + w] = lo;
      ((int*)st)[ST_TIES + w] = ksel - (S_ - cle);
    }
  }
}

// ---------- select ----------
__global__ __launch_bounds__(1024) void kt_select(const float* __restrict__ imp, const u32* __restrict__ st,
    int* __restrict__ sel, u32* __restrict__ lab){
  int b = blockIdx.x, tid = threadIdx.x, lane = tid & 63, w = tid >> 6;
  u32 vkey = st[ST_VKEY + b];
  int ties = ((const int*)st)[ST_TIES + b];
  int s0 = tid*2, s1 = s0 + 1;
  float f0 = imp[(size_t)b*S_ + s0], f1 = imp[(size_t)b*S_ + s1];
  lab[(size_t)b*S_ + s0] = (f0 > 0.7f) ? 2u : ((f0 >= 0.3f) ? 1u : 0u);
  lab[(size_t)b*S_ + s1] = (f1 > 0.7f) ? 2u : ((f1 >= 0.3f) ? 1u : 0u);
  u32 k0 = fkey(f0), k1 = fkey(f1);
  int g0 = (k0 > vkey), g1 = (k1 > vkey);
  int t0 = (k0 == vkey), t1 = (k1 == vkey);
  __shared__ int wtot[16];
  int tsum = t0 + t1, incl = tsum;
  #pragma unroll
  for (int off=1; off<64; off<<=1){ int nv = __shfl_up(incl, off); if (lane >= off) incl += nv; }
  if (lane == 63) wtot[w] = incl;
  __syncthreads();
  int woff = 0;
  for (int i=0;i<w;i++) woff += wtot[i];
  int tie0 = woff + incl - tsum;
  int tie1 = tie0 + t0;
  int sf0 = g0 | (t0 & ((tie0 < ties) ? 1 : 0));
  int sf1 = g1 | (t1 & ((tie1 < ties) ? 1 : 0));
  __syncthreads();
  int ssum = sf0 + sf1; incl = ssum;
  #pragma unroll
  for (int off=1; off<64; off<<=1){ int nv = __shfl_up(incl, off); if (lane >= off) incl += nv; }
  if (lane == 63) wtot[w] = incl;
  __syncthreads();
  woff = 0;
  for (int i=0;i<w;i++) woff += wtot[i];
  int p0 = woff + incl - ssum;
  if (sf0) sel[(size_t)b*S_ + p0] = s0;
  if (sf1) sel[(size_t)b*S_ + p0 + sf0] = s1;
}

// ---------- per-level global min/max: 256 blocks (atomic contention fix) ----------
__global__ __launch_bounds__(256) void kt_minmax(const float* __restrict__ Kf, const float* __restrict__ Vf,
    const u32* __restrict__ lab, u32* __restrict__ st){
  u32 mn[6], mx[6];
  #pragma unroll
  for (int q=0;q<6;q++){ mn[q] = 0xFFFFFFFFu; mx[q] = 0u; }
  const int n4 = NTOK * HD_ / 4;
  for (int i = blockIdx.x*blockDim.x + threadIdx.x; i < n4; i += gridDim.x*blockDim.x){
    u32 l = min(lab[i >> 8], 2u);
    float4 kv = ((const float4*)Kf)[i];
    float4 vv = ((const float4*)Vf)[i];
    u32 a0=fkey(kv.x), a1=fkey(kv.y), a2=fkey(kv.z), a3=fkey(kv.w);
    u32 klo = min(min(a0,a1),min(a2,a3)), khi = max(max(a0,a1),max(a2,a3));
    if (klo < mn[l]) mn[l] = klo;
    if (khi > mx[l]) mx[l] = khi;
    u32 b0=fkey(vv.x), b1=fkey(vv.y), b2=fkey(vv.z), b3=fkey(vv.w);
    u32 vlo = min(min(b0,b1),min(b2,b3)), vhi = max(max(b0,b1),max(b2,b3));
    if (vlo < mn[3+l]) mn[3+l] = vlo;
    if (vhi > mx[3+l]) mx[3+l] = vhi;
  }
  #pragma unroll
  for (int q=0;q<6;q++){
    #pragma unroll
    for (int off=32; off; off>>=1){
      u32 om = (u32)__shfl_xor((int)mn[q], off); if (om < mn[q]) mn[q] = om;
      u32 oM = (u32)__shfl_xor((int)mx[q], off); if (oM > mx[q]) mx[q] = oM;
    }
  }
  __shared__ u32 smn[4][6], smx[4][6];
  int lane = threadIdx.x & 63, w = threadIdx.x >> 6;
  if (lane == 0){
    #pragma unroll
    for (int q=0;q<6;q++){ smn[w][q]=mn[q]; smx[w][q]=mx[q]; }
  }
  __syncthreads();
  if (threadIdx.x < 6){
    int q = threadIdx.x;
    u32 m = smn[0][q], M = smx[0][q];
    #pragma unroll
    for (int i=1;i<4;i++){ if (smn[i][q] < m) m = smn[i][q]; if (smx[i][q] > M) M = smx[i][q]; }
    int minSlot = ST_MM + ((q < 3) ? q : q + 3);
    atomicMin(&st[minSlot], m);
    atomicMax(&st[minSlot + 3], M);
  }
}

// ---------- scales from ST_MM (bit-identical to former kt_finalize math) ----------
__device__ __forceinline__ void scales_for(const u32* st, u32 l, float &qmx,
    float &sK, float &zK, float &sV, float &zV){
  qmx = (l==0) ? 3.f : (l==1) ? 15.f : 255.f;
  u32 mnk = st[ST_MM + l], mxk = st[ST_MM + 3 + l];
  sK = 1.f; zK = 0.f;
  if (!(mnk == 0xFFFFFFFFu || mxk == 0u)){
    float tmn = keyf(mnk), tmx = keyf(mxk);
    if (tmx != tmn){ sK = __fdiv_rn(__fsub_rn(tmx, tmn), qmx); zK = __fdiv_rn(-tmn, sK); }
  }
  u32 mnv = st[ST_MM + 6 + l], mxv = st[ST_MM + 9 + l];
  sV = 1.f; zV = 0.f;
  if (!(mnv == 0xFFFFFFFFu || mxv == 0u)){
    float tmn = keyf(mnv), tmx = keyf(mxv);
    if (tmx != tmn){ sV = __fdiv_rn(__fsub_rn(tmx, tmn), qmx); zV = __fdiv_rn(-tmn, sV); }
  }
}

__device__ __forceinline__ float dqz(float x, float s, float z, float q){
  float t = rintf(__fadd_rn(__fdiv_rn(x, s), z));
  t = fminf(fmaxf(t, 0.f), q);
  return __fmul_rn(__fsub_rn(t, z), s);
}

// ---------- gather + quant-dequant; K hi/lo, V single (scales inlined) ----------
__global__ __launch_bounds__(256) void kt_buildck(const float* __restrict__ Kf, const float* __restrict__ Vf,
    const int* __restrict__ sel, const u32* __restrict__ lab, const u32* __restrict__ st,
    u16* __restrict__ ckh, u16* __restrict__ ckl, u16* __restrict__ cvb){
  int b = blockIdx.z, j = blockIdx.y;
  int ksel = ((const int*)st)[ST_KSEL], kpad = ((const int*)st)[ST_KPAD];
  if (j >= kpad) return;
  int dd = threadIdx.x * 4;
  size_t oo = ((size_t)b*S_ + j)*HD_ + dd;
  if (j >= ksel){
    u16x4 z4 = {0,0,0,0};
    *(u16x4*)(ckh + oo) = z4;
    *(u16x4*)(ckl + oo) = z4;
    *(u16x4*)(cvb + oo) = z4;
    return;
  }
  int s = sel[(size_t)b*S_ + j];
  u32 l = min(lab[(size_t)b*S_ + s], 2u);
  float qmx, sK, zK, sV, zV;
  scales_for(st, l, qmx, sK, zK, sV, zV);
  float4 kv = *(const float4*)(Kf + ((size_t)b*S_ + s)*HD_ + dd);
  float4 vv = *(const float4*)(Vf + ((size_t)b*S_ + s)*HD_ + dd);
  float kd0 = dqz(kv.x,sK,zK,qmx), kd1 = dqz(kv.y,sK,zK,qmx), kd2 = dqz(kv.z,sK,zK,qmx), kd3 = dqz(kv.w,sK,zK,qmx);
  u16 h0 = f2bf(kd0), h1 = f2bf(kd1), h2 = f2bf(kd2), h3 = f2bf(kd3);
  u16x4 kh = {h0, h1, h2, h3};
  u16x4 kl = {f2bf(kd0 - bf2f(h0)), f2bf(kd1 - bf2f(h1)), f2bf(kd2 - bf2f(h2)), f2bf(kd3 - bf2f(h3))};
  u16x4 vo = {f2bf(dqz(vv.x,sV,zV,qmx)), f2bf(dqz(vv.y,sV,zV,qmx)),
              f2bf(dqz(vv.z,sV,zV,qmx)), f2bf(dqz(vv.w,sV,zV,qmx))};
  *(u16x4*)(ckh + oo) = kh;
  *(u16x4*)(ckl + oo) = kl;
  *(u16x4*)(cvb + oo) = vo;
}

// ---------- bf16 transpose of V ----------
__global__ __launch_bounds__(256) void kt_cvt(const u16* __restrict__ cvb, u16* __restrict__ cvT,
    const u32* __restrict__ st){
  int kpad = ((const int*)st)[ST_KPAD];
  int j0 = blockIdx.x*32;
  if (j0 >= kpad) return;
  int d0 = blockIdx.y*32, b = blockIdx.z;
  __shared__ u16 t[32][33];
  int tx = threadIdx.x, ty = threadIdx.y;
  #pragma unroll
  for (int i=0;i<32;i+=8) t[ty+i][tx] = cvb[((size_t)b*S_ + j0+ty+i)*HD_ + d0+tx];
  __syncthreads();
  #pragma unroll
  for (int i=0;i<32;i+=8) cvT[((size_t)b*HD_ + d0+ty+i)*S_ + j0+tx] = t[tx][ty+i];
}

// ---------- flash attention, QBLK=128, double-buffered, truncation P-split ----------
// (round-16 configuration: best measured)
#define ATTN_QSTEP(KSH, KSL, VS, QA0, QA1, MRUN, LRUN, OARR, MASKQ)                \
  {                                                                                \
    f32x4 sc[4];                                                                   \
    const int fro = ((lane>>3)&1)*512 + (((lane>>4)*8 + (lane&7))<<3);             \
    __builtin_amdgcn_s_setprio(1);                                                 \
    _Pragma("unroll")                                                              \
    for (int nt=0; nt<4; nt++){                                                    \
      int ro = nt*1024 + fro;                                                      \
      bf16x8 bh0 = *(const bf16x8*)(KSH + ro);                                     \
      bf16x8 bh1 = *(const bf16x8*)(KSH + ro + 256);                               \
      bf16x8 bl0 = *(const bf16x8*)(KSL + ro);                                     \
      bf16x8 bl1 = *(const bf16x8*)(KSL + ro + 256);                               \
      f32x4 zzv = (f32x4){0.f,0.f,0.f,0.f};                                        \
      zzv = __builtin_amdgcn_mfma_f32_16x16x32_bf16(QA0, bh0, zzv, 0, 0, 0);       \
      zzv = __builtin_amdgcn_mfma_f32_16x16x32_bf16(QA1, bh1, zzv, 0, 0, 0);       \
      zzv = __builtin_amdgcn_mfma_f32_16x16x32_bf16(QA0, bl0, zzv, 0, 0, 0);       \
      zzv = __builtin_amdgcn_mfma_f32_16x16x32_bf16(QA1, bl1, zzv, 0, 0, 0);       \
      sc[nt] = zzv;                                                                \
    }                                                                              \
    __builtin_amdgcn_s_setprio(0);                                                 \
    float cm[4] = {NEGBIG,NEGBIG,NEGBIG,NEGBIG};                                   \
    _Pragma("unroll")                                                              \
    for (int nt=0; nt<4; nt++){                                                    \
      bool valid = MASKQ ? ((c*64 + nt*16 + (lane&15)) < ksel) : true;             \
      _Pragma("unroll")                                                            \
      for (int r=0;r<4;r++){                                                       \
        float x = valid ? sc[nt][r]*0.125f : NEGBIG;                               \
        sc[nt][r] = x;                                                             \
        cm[r] = fmaxf(cm[r], x);                                                   \
      }                                                                            \
    }                                                                              \
    _Pragma("unroll")                                                              \
    for (int r=0;r<4;r++){                                                         \
      _Pragma("unroll")                                                            \
      for (int off=1; off<16; off<<=1) cm[r] = fmaxf(cm[r], __shfl_xor(cm[r], off));\
    }                                                                              \
    float alpha[4], rs[4];                                                         \
    _Pragma("unroll")                                                              \
    for (int r=0;r<4;r++){                                                         \
      float mn = fmaxf(MRUN[r], cm[r]);                                            \
      alpha[r] = __expf(MRUN[r] - mn);                                             \
      MRUN[r] = mn;                                                                \
      rs[r] = 0.f;                                                                 \
    }                                                                              \
    _Pragma("unroll")                                                              \
    for (int nt=0; nt<4; nt++)                                                     \
      _Pragma("unroll")                                                            \
      for (int r=0;r<4;r++){                                                       \
        float p = __expf(sc[nt][r] - MRUN[r]);                                     \
        sc[nt][r] = p;                                                             \
        rs[r] += p;                                                                \
      }                                                                            \
    _Pragma("unroll")                                                              \
    for (int r=0;r<4;r++){                                                         \
      _Pragma("unroll")                                                            \
      for (int off=1; off<16; off<<=1) rs[r] += __shfl_xor(rs[r], off);            \
      LRUN[r] = LRUN[r]*alpha[r] + rs[r];                                          \
    }                                                                              \
    _Pragma("unroll")                                                              \
    for (int dt=0; dt<4; dt++)                                                     \
      _Pragma("unroll")                                                            \
      for (int r=0;r<4;r++) OARR[dt][r] *= alpha[r];                               \
    _Pragma("unroll")                                                              \
    for (int nt=0; nt<4; nt++)                                                     \
      _Pragma("unroll")                                                            \
      for (int r=0;r<4;r++){                                                       \
        float p = sc[nt][r];                                                       \
        u32 pu; __builtin_memcpy(&pu, &p, 4);                                      \
        u32 hm = pu & 0xFFFF0000u;                                                 \
        float rh; __builtin_memcpy(&rh, &hm, 4);                                   \
        float rl = p - rh;                                                         \
        u32 lu; __builtin_memcpy(&lu, &rl, 4);                                     \
        int o2 = (((lane>>4)<<2) + r)*72 + nt*16 + (lane&15);                      \
        pwh[o2] = (u16)(pu >> 16);                                                 \
        pwl[o2] = (u16)(lu >> 16);                                                 \
      }                                                                            \
    bf16x8 pa0h = *(const bf16x8*)(pwh + (lane&15)*72 + ((lane>>4)<<3));           \
    bf16x8 pa1h = *(const bf16x8*)(pwh + (lane&15)*72 + 32 + ((lane>>4)<<3));      \
    bf16x8 pa0l = *(const bf16x8*)(pwl + (lane&15)*72 + ((lane>>4)<<3));           \
    bf16x8 pa1l = *(const bf16x8*)(pwl + (lane&15)*72 + 32 + ((lane>>4)<<3));      \
    __builtin_amdgcn_s_setprio(1);                                                 \
    _Pragma("unroll")                                                              \
    for (int dt=0; dt<4; dt++){                                                    \
      int vo = dt*1024 + fro;                                                      \
      bf16x8 v0 = *(const bf16x8*)(VS + vo);                                       \
      bf16x8 v1 = *(const bf16x8*)(VS + vo + 256);                                 \
      OARR[dt] = __builtin_amdgcn_mfma_f32_16x16x32_bf16(pa0h, v0, OARR[dt], 0, 0, 0);\
      OARR[dt] = __builtin_amdgcn_mfma_f32_16x16x32_bf16(pa1h, v1, OARR[dt], 0, 0, 0);\
      OARR[dt] = __builtin_amdgcn_mfma_f32_16x16x32_bf16(pa0l, v0, OARR[dt], 0, 0, 0);\
      OARR[dt] = __builtin_amdgcn_mfma_f32_16x16x32_bf16(pa1l, v1, OARR[dt], 0, 0, 0);\
    }                                                                              \
    __builtin_amdgcn_s_setprio(0);                                                 \
  }

__global__ __launch_bounds__(256) void kt_attn(const u16* __restrict__ qb, const u16* __restrict__ ckh,
    const u16* __restrict__ ckl, const u16* __restrict__ cvT, const u32* __restrict__ st,
    u16* __restrict__ ao){
  int m0 = blockIdx.x * 128, h = blockIdx.y, b = blockIdx.z;
  int ksel = ((const int*)st)[ST_KSEL], nck = ((const int*)st)[ST_NCK];
  int tid = threadIdx.x, lane = tid & 63, w = tid >> 6;
  __shared__ u16 cksh[2*4096];
  __shared__ u16 cksl[2*4096];
  __shared__ u16 cvs[2*4096];
  __shared__ u16 psh[4][16*72];
  __shared__ u16 psl[4][16*72];
  const u16* gp[6];
  u16* lp[6];
  int adv[6];
  #pragma unroll
  for (int i = 0; i < 6; i++){
    int t = w + 4*i, pl = t >> 3, g = t & 7;
    if (pl == 0){
      gp[i] = ckh + ((size_t)b*S_ + g*8 + (lane&7))*HD_ + h*64 + ((lane>>3)<<3);
      lp[i] = cksh + g*512;
      adv[i] = 64*HD_;
    } else if (pl == 1){
      gp[i] = ckl + ((size_t)b*S_ + g*8 + (lane&7))*HD_ + h*64 + ((lane>>3)<<3);
      lp[i] = cksl + g*512;
      adv[i] = 64*HD_;
    } else {
      gp[i] = cvT + ((size_t)b*HD_ + h*64 + g*8 + (lane&7))*S_ + ((lane>>3)<<3);
      lp[i] = cvs + g*512;
      adv[i] = 64;
    }
  }
  const u16* qrow0 = qb + ((size_t)b*S_ + m0      + w*16 + (lane&15))*HD_ + h*64;
  const u16* qrow1 = qb + ((size_t)b*S_ + m0 + 64 + w*16 + (lane&15))*HD_ + h*64;
  bf16x8 q0a = *(const bf16x8*)(qrow0 + ((lane>>4)<<3));
  bf16x8 q0b = *(const bf16x8*)(qrow0 + 32 + ((lane>>4)<<3));
  bf16x8 q1a = *(const bf16x8*)(qrow1 + ((lane>>4)<<3));
  bf16x8 q1b = *(const bf16x8*)(qrow1 + 32 + ((lane>>4)<<3));
  f32x4 o0[4], o1[4];
  #pragma unroll
  for (int dt=0; dt<4; dt++){ o0[dt] = (f32x4){0.f,0.f,0.f,0.f}; o1[dt] = (f32x4){0.f,0.f,0.f,0.f}; }
  float m0r[4] = {NEGBIG,NEGBIG,NEGBIG,NEGBIG};
  float m1r[4] = {NEGBIG,NEGBIG,NEGBIG,NEGBIG};
  float l0r[4] = {0.f,0.f,0.f,0.f};
  float l1r[4] = {0.f,0.f,0.f,0.f};
  u16* pwh = &psh[w][0];
  u16* pwl = &psl[w][0];
  const int nfull = ksel >> 6;
  // prologue: stage chunk 0 into buffer 0
  #pragma unroll
  for (int i = 0; i < 6; i++){ gload16(gp[i], lp[i]); gp[i] += adv[i]; }
  __syncthreads();
  for (int c = 0; c < nck; c++){
    int cur = c & 1, nxt = cur ^ 1;
    if (c + 1 < nck){
      #pragma unroll
      for (int i = 0; i < 6; i++){ gload16(gp[i], lp[i] + nxt*4096); gp[i] += adv[i]; }
    }
    const u16* ksh = cksh + cur*4096;
    const u16* ksl = cksl + cur*4096;
    const u16* vs  = cvs  + cur*4096;
    if (c < nfull){
      ATTN_QSTEP(ksh, ksl, vs, q0a, q0b, m0r, l0r, o0, 0)
      ATTN_QSTEP(ksh, ksl, vs, q1a, q1b, m1r, l1r, o1, 0)
    } else {
      ATTN_QSTEP(ksh, ksl, vs, q0a, q0b, m0r, l0r, o0, 1)
      ATTN_QSTEP(ksh, ksl, vs, q1a, q1b, m1r, l1r, o1, 1)
    }
    __syncthreads();
  }
  #pragma unroll
  for (int dt=0; dt<4; dt++)
    #pragma unroll
    for (int r=0;r<4;r++){
      int dd = dt*16 + (lane&15);
      int row0 = m0 + w*16 + ((lane>>4)<<2) + r;
      float v0 = o0[dt][r] / fmaxf(l0r[r], 1e-37f);
      ao[((size_t)b*S_ + row0)*HD_ + h*64 + dd] = f2bf(v0);
      int row1 = row0 + 64;
      float v1 = o1[dt][r] / fmaxf(l1r[r], 1e-37f);
      ao[((size_t)b*S_ + row1)*HD_ + h*64 + dd] = f2bf(v1);
    }
}

// ---------- launch ----------
extern "C" void kernel_launch(void* const* d_in, const int* in_sizes, int n_in,
                              void* d_out, int out_size, void* d_ws, size_t ws_size,
                              hipStream_t stream){
  if (ws_size < WS_NEED) return;
  const float* hid  = (const float*)d_in[0];
  const float* Wq   = (const float*)d_in[1];
  const float* Wk   = (const float*)d_in[2];
  const float* Wv   = (const float*)d_in[3];
  const float* Wo   = (const float*)d_in[4];
  const float* wimp = (const float*)d_in[5];
  const float* bimp = (const float*)d_in[6];
  const int*   pm   = (const int*)d_in[7];

  char* ws = (char*)d_ws;
  float* Q0  = (float*)(ws + OFF_Q0);
  float* Kf  = (float*)(ws + OFF_K);
  float* Vf  = (float*)(ws + OFF_V);
  u16*   HS  = (u16*)(ws + OFF_HS);
  u16*   WP  = (u16*)(ws + OFF_WP);
  u16*   QB  = (u16*)(ws + OFF_QB);
  float* IMP = (float*)(ws + OFF_IMP);
  u32*   LAB = (u32*)(ws + OFF_LAB);
  int*   SEL = (int*)(ws + OFF_SEL);
  u32*   ST  = (u32*)(ws + OFF_ST);
  // aliases (lifetime-checked):
  float* K0T = (float*)(ws + OFF_HS);                 // HS dead after gemm_q/kv
  u16*   CKH = (u16*)(ws + OFF_HS);                   // from buildck on
  u16*   CKL = (u16*)(ws + OFF_HS + 16777216ull);
  u16*   CVB = (u16*)(ws + OFF_HS + 33554432ull);
  u16*   CVT = (u16*)(ws + OFF_V);                    // Vf dead after buildck
  u16*   AO  = (u16*)(ws + OFF_K);                    // Kf dead after buildck
  u16*   WOT = (u16*)(ws + OFF_Q0);                   // Q0 dead after imp

  dim3 tb32(32, 8);
  kt_split_h<<<8192, 256, 0, stream>>>(hid, HS, HS + HSPL, HS + 2u*HSPL, ST);
  kt_twts3<<<dim3(32,32,3), tb32, 0, stream>>>(Wk, Wv, Wq, WP);
  kt_gemm_kv1<<<dim3(8,64), 256, 0, stream>>>(HS, WP+WKH_O, WP+WKM_O, WP+WKL_O, Kf);
  kt_gemm_kv1<<<dim3(8,64), 256, 0, stream>>>(HS, WP+WVH_O, WP+WVM_O, WP+WVL_O, Vf);
  kt_gemm_q<<<dim3(8,64), 256, 0, stream>>>(HS, WP, QB, Q0);
  kt_k0t<<<dim3(64,2,4), tb32, 0, stream>>>(Kf, K0T);
  kt_bias<<<4, 1024, 0, stream>>>(Q0, wimp, bimp, ST);
  kt_imp<<<dim3(128,4), 256, 0, stream>>>(Q0, K0T, pm, ST, IMP);
  kt_stats<<<1, 1024, 0, stream>>>(IMP, ST);
  kt_select<<<4, 1024, 0, stream>>>(IMP, ST, SEL, LAB);
  kt_minmax<<<256, 256, 0, stream>>>(Kf, Vf, LAB, ST);
  kt_buildck<<<dim3(1,2048,4), 256, 0, stream>>>(Kf, Vf, SEL, LAB, ST, CKH, CKL, CVB);
  kt_cvt<<<dim3(64,32,4), tb32, 0, stream>>>(CVB, CVT, ST);
  kt_attn<<<dim3(16,16,4), 256, 0, stream>>>(QB, CKH, CKL, CVT, ST, AO);
  kt_twto<<<dim3(32,32), tb32, 0, stream>>>(Wo, WOT);
  kt_gemm_o<<<dim3(8,64), 256, 0, stream>>>(AO, WOT, (float*)d_out);
}